// Round 13
// baseline (246.769 us; speedup 1.0000x reference)
//
#include <hip/hip_runtime.h>
#include <hip/hip_bf16.h>

// Problem: CausalSelfAttention  B=2, T=2048, C=1024, H=16, D=64
// Round 25: attn KVBLK 64->128. R24: qkv_qk 64.5->61.2 (BK=64 kept); attn
// (61us, VALU 34 > Mfma 23) is per-iteration-overhead bound: 33 iters of
// {2 barriers, prefetch issue, 4+ shuffles, tree reductions, rescale checks}.
// This round halves the iteration count: 128-key chunks, 17 chunks/block
// (exactly, for every pair (j,31-j); dual-chunks 9/CU slot, balance kept).
// Masking: chunk c==qt>>1 is diagonal; mask key-in-chunk > (qt&1)*64+qg.
// LDS 40->80KB (still 2 blocks/CU, grid-pinned). S frags 8/chain; tree
// reductions use 8 temps (VGPR ~200). Swizzle/Ps/Vt/epilogue = verified
// patterns with t 4->8. exp2/MFMA totals unchanged; barriers 66->34.
// qkv_qk/qkv_v/proj = R24 (BK=64, XCD remap, 0-conflict). cvt_all = R22.
// ws (62 MB): Qh 8|Ql 8|Kh 8|Kl 8|xh 8(->Yb)|xl 8(->VT)|WaTh 6|WaTl 6|WpT 2

#define B_  2
#define T_  2048
#define C_  1024
#define H_  16
#define D_  64
#define M_  (B_ * T_)      // 4096
#define N3_ (3 * C_)       // 3072

typedef __attribute__((ext_vector_type(8))) short s16x8;
typedef __attribute__((ext_vector_type(4))) short s16x4;
typedef __attribute__((ext_vector_type(4))) float f32x4;

typedef const __attribute__((address_space(1))) unsigned int gu32_t;
typedef __attribute__((address_space(3))) unsigned int lu32_t;

#define MFMA16(a, b, c) __builtin_amdgcn_mfma_f32_16x16x32_bf16(a, b, c, 0, 0, 0)

__device__ __forceinline__ void gload_lds16(const short* g, short* l) {
    __builtin_amdgcn_global_load_lds((gu32_t*)g, (lu32_t*)l, 16, 0, 0);
}

__device__ __forceinline__ float b2f(unsigned short u) {
    return __uint_as_float(((unsigned)u) << 16);
}
__device__ __forceinline__ unsigned short f2b(float f) {   // RNE bf16 round
    unsigned u = __float_as_uint(f);
    return (unsigned short)((u + 0x7FFFu + ((u >> 16) & 1u)) >> 16);
}
__device__ __forceinline__ float fexp2(float x) {
#if __has_builtin(__builtin_amdgcn_exp2f)
    return __builtin_amdgcn_exp2f(x);
#else
    return exp2f(x);
#endif
}

// ---------------------------------------------------------------------------
// cvt_all: one dispatch for all input conversions (grid 3072).
// ---------------------------------------------------------------------------
__global__ __launch_bounds__(256) void cvt_all(
    const float* __restrict__ x,  short* __restrict__ xh,   short* __restrict__ xl,
    const float* __restrict__ Wa, short* __restrict__ WaTh, short* __restrict__ WaTl,
    const float* __restrict__ Wp, short* __restrict__ WpT)
{
    __shared__ short th[64][80];
    __shared__ short tl[64][80];
    const int tid = threadIdx.x;
    const int bid = blockIdx.x;

    if (bid < 2048) {
        int i = (bid * 256 + tid) * 8;
        float4 a = *(const float4*)&x[i];
        float4 b = *(const float4*)&x[i + 4];
        float v[8] = {a.x, a.y, a.z, a.w, b.x, b.y, b.z, b.w};
        s16x8 h, l;
        #pragma unroll
        for (int j = 0; j < 8; j++) {
            unsigned short hb = f2b(v[j]);
            h[j] = (short)hb;
            l[j] = (short)f2b(v[j] - b2f(hb));
        }
        *(s16x8*)&xh[i] = h;
        *(s16x8*)&xl[i] = l;
        return;
    }

    if (bid < 2816) {
        int r  = bid - 2048;            // 0..767
        int bx = r % 48, by = r / 48;   // (N3_/64, C_/64)
        const int k0 = by * 64, n0 = bx * 64;
        const int R = C_, Cn = N3_;
        {
            int rl = tid >> 4, cl = (tid & 15) * 4;
            #pragma unroll
            for (int i = 0; i < 4; i++) {
                int kr = rl + i * 16;
                float4 v4 = *(const float4*)&Wa[(size_t)(k0 + kr) * Cn + n0 + cl];
                float v[4] = {v4.x, v4.y, v4.z, v4.w};
                #pragma unroll
                for (int j = 0; j < 4; j++) {
                    unsigned short hb = f2b(v[j]);
                    th[cl + j][kr] = (short)hb;
                    tl[cl + j][kr] = (short)f2b(v[j] - b2f(hb));
                }
            }
        }
        __syncthreads();
        {
            int ro = tid >> 2, co = (tid & 3) * 16;
            *(s16x8*)&WaTh[(size_t)(n0 + ro) * R + k0 + co]     = *(s16x8*)&th[ro][co];
            *(s16x8*)&WaTh[(size_t)(n0 + ro) * R + k0 + co + 8] = *(s16x8*)&th[ro][co + 8];
            *(s16x8*)&WaTl[(size_t)(n0 + ro) * R + k0 + co]     = *(s16x8*)&tl[ro][co];
            *(s16x8*)&WaTl[(size_t)(n0 + ro) * R + k0 + co + 8] = *(s16x8*)&tl[ro][co + 8];
        }
        return;
    }

    {
        int r  = bid - 2816;            // 0..255
        int bx = r & 15, by = r >> 4;   // (C_/64, C_/64)
        const int k0 = by * 64, n0 = bx * 64;
        const int R = C_, Cn = C_;
        {
            int rl = tid >> 4, cl = (tid & 15) * 4;
            #pragma unroll
            for (int i = 0; i < 4; i++) {
                int kr = rl + i * 16;
                float4 v = *(const float4*)&Wp[(size_t)(k0 + kr) * Cn + n0 + cl];
                th[cl + 0][kr] = (short)f2b(v.x);
                th[cl + 1][kr] = (short)f2b(v.y);
                th[cl + 2][kr] = (short)f2b(v.z);
                th[cl + 3][kr] = (short)f2b(v.w);
            }
        }
        __syncthreads();
        {
            int ro = tid >> 2, co = (tid & 3) * 16;
            *(s16x8*)&WpT[(size_t)(n0 + ro) * R + k0 + co]     = *(s16x8*)&th[ro][co];
            *(s16x8*)&WpT[(size_t)(n0 + ro) * R + k0 + co + 8] = *(s16x8*)&th[ro][co + 8];
        }
    }
}

// ---------------------------------------------------------------------------
// qkv_qk: Q,K columns (N=2048), bf16x3, hi/lo scatter. 128x128 tile, XCD
// remap, BK=64 panels, LDS 64 KB, 0-conflict granule swizzle. (R24)
// ---------------------------------------------------------------------------
__global__ __launch_bounds__(256) void qkv_qk(
    const short* __restrict__ Ah, const short* __restrict__ Al,
    const short* __restrict__ BTh, const short* __restrict__ BTl,
    const float* __restrict__ bias,
    short* __restrict__ Qh, short* __restrict__ Ql,
    short* __restrict__ Kh, short* __restrict__ Kl)
{
    __shared__ short Ash[2][128 * 32], Asl[2][128 * 32];
    __shared__ short Bsh[2][128 * 32], Bsl[2][128 * 32];   // 64 KB

    const int tid  = threadIdx.x;
    const int wave = tid >> 6, lane = tid & 63;
    const int wm = wave >> 1, wn = wave & 1;
    const int lm = lane & 15, lq = lane >> 4;
    const int fid = blockIdx.y * 16 + blockIdx.x;
    const int wg  = (fid & 7) * 64 + (fid >> 3);
    const int n0  = (wg & 15) * 128;
    const int m0  = (wg >> 4) * 128;
    const int gr  = (lane >> 2);
    const int gc  = (((lane & 3) ^ ((lane >> 3) & 3)) << 3);
    const int sg  = ((lq ^ ((lm >> 1) & 3)) << 3);

    f32x4 acc[4][4] = {};

    for (int k0 = 0; k0 < C_; k0 += 64) {
        __syncthreads();
        #pragma unroll
        for (int p = 0; p < 2; p++) {
            int kp = k0 + p * 32;
            #pragma unroll
            for (int j = 0; j < 2; j++) {
                int s = wave * 2 + j;
                int row = s * 16 + gr;
                size_t ga = (size_t)(m0 + row) * C_ + kp + gc;
                size_t gb = (size_t)(n0 + row) * C_ + kp + gc;
                gload_lds16(&Ah[ga],  &Ash[p][s * 512]);
                gload_lds16(&Al[ga],  &Asl[p][s * 512]);
                gload_lds16(&BTh[gb], &Bsh[p][s * 512]);
                gload_lds16(&BTl[gb], &Bsl[p][s * 512]);
            }
        }
        __syncthreads();

        #pragma unroll
        for (int p = 0; p < 2; p++) {
            s16x8 ah[4], al[4], bh[4], bl[4];
            #pragma unroll
            for (int mi = 0; mi < 4; mi++) {
                int r = wm * 64 + mi * 16 + lm;
                ah[mi] = *(const s16x8*)&Ash[p][r * 32 + sg];
                al[mi] = *(const s16x8*)&Asl[p][r * 32 + sg];
            }
            #pragma unroll
            for (int nj = 0; nj < 4; nj++) {
                int r = wn * 64 + nj * 16 + lm;
                bh[nj] = *(const s16x8*)&Bsh[p][r * 32 + sg];
                bl[nj] = *(const s16x8*)&Bsl[p][r * 32 + sg];
            }
            #pragma unroll
            for (int mi = 0; mi < 4; mi++)
                #pragma unroll
                for (int nj = 0; nj < 4; nj++) {
                    acc[mi][nj] = MFMA16(ah[mi], bh[nj], acc[mi][nj]);
                    acc[mi][nj] = MFMA16(ah[mi], bl[nj], acc[mi][nj]);
                    acc[mi][nj] = MFMA16(al[mi], bh[nj], acc[mi][nj]);
                }
        }
    }

    #pragma unroll
    for (int nj = 0; nj < 4; nj++) {
        int n = n0 + wn * 64 + nj * 16 + lm;
        float bv = bias[n];
        int isK = n >> 10;
        int c = n & (C_ - 1);
        int h = c >> 6, d = c & (D_ - 1);
        short* dh = isK ? Kh : Qh;
        short* dl = isK ? Kl : Ql;
        // Q carries sqrt(D)=8 and log2(e): softmax runs in exp2 domain
        float scale = isK ? 1.0f : 11.541560327111708f;   // 8*log2(e)
        #pragma unroll
        for (int mi = 0; mi < 4; mi++) {
            #pragma unroll
            for (int r = 0; r < 4; r++) {
                int m  = m0 + wm * 64 + mi * 16 + lq * 4 + r;
                int bb = m >> 11, t = m & (T_ - 1);
                float v = (acc[mi][nj][r] + bv) * scale;
                size_t idx = (((size_t)bb * H_ + h) * T_ + t) * D_ + d;
                unsigned short hb = f2b(v);
                dh[idx] = (short)hb;
                dl[idx] = (short)f2b(v - b2f(hb));
            }
        }
    }
}

// ---------------------------------------------------------------------------
// qkv_v: V columns (N=1024), single bf16, scatter TRANSPOSED -> VT [B,H,D,T].
// 64x128 tile, XCD remap, BK=64 panels, LDS 24 KB. (R24)
// ---------------------------------------------------------------------------
__global__ __launch_bounds__(256, 4) void qkv_v(
    const short* __restrict__ Ah, const short* __restrict__ BTh,
    const float* __restrict__ bias, short* __restrict__ VT)
{
    __shared__ short Ash[2][64 * 32];    // 8 KB
    __shared__ short Bsh[2][128 * 32];   // 16 KB

    const int tid  = threadIdx.x;
    const int wave = tid >> 6, lane = tid & 63;
    const int wm = wave >> 1, wn = wave & 1;
    const int lm = lane & 15, lq = lane >> 4;
    const int fid = blockIdx.y * 8 + blockIdx.x;
    const int wg  = (fid & 7) * 64 + (fid >> 3);
    const int n0  = (wg & 7) * 128;
    const int m0  = (wg >> 3) * 64;
    const int gr  = (lane >> 2);
    const int gc  = (((lane & 3) ^ ((lane >> 3) & 3)) << 3);
    const int sg  = ((lq ^ ((lm >> 1) & 3)) << 3);

    f32x4 acc[2][4] = {};

    for (int k0 = 0; k0 < C_; k0 += 64) {
        __syncthreads();
        #pragma unroll
        for (int p = 0; p < 2; p++) {
            int kp = k0 + p * 32;
            int rowA = wave * 16 + gr;
            gload_lds16(&Ah[(size_t)(m0 + rowA) * C_ + kp + gc], &Ash[p][wave * 512]);
            #pragma unroll
            for (int j = 0; j < 2; j++) {
                int s = wave * 2 + j;
                int rowB = s * 16 + gr;
                gload_lds16(&BTh[(size_t)(n0 + rowB) * C_ + kp + gc], &Bsh[p][s * 512]);
            }
        }
        __syncthreads();

        #pragma unroll
        for (int p = 0; p < 2; p++) {
            s16x8 af[2], bfr[4];
            #pragma unroll
            for (int mi = 0; mi < 2; mi++)
                af[mi] = *(const s16x8*)&Ash[p][(wm * 32 + mi * 16 + lm) * 32 + sg];
            #pragma unroll
            for (int nj = 0; nj < 4; nj++)
                bfr[nj] = *(const s16x8*)&Bsh[p][(wn * 64 + nj * 16 + lm) * 32 + sg];
            #pragma unroll
            for (int mi = 0; mi < 2; mi++)
                #pragma unroll
                for (int nj = 0; nj < 4; nj++)
                    acc[mi][nj] = MFMA16(af[mi], bfr[nj], acc[mi][nj]);
        }
    }

    #pragma unroll
    for (int nj = 0; nj < 4; nj++) {
        int n = n0 + wn * 64 + nj * 16 + lm;    // [0, 1024) V channel
        float bv = bias[n];
        int h = n >> 6, d = n & (D_ - 1);
        #pragma unroll
        for (int mi = 0; mi < 2; mi++) {
            #pragma unroll
            for (int r = 0; r < 4; r++) {
                int m  = m0 + wm * 32 + mi * 16 + lq * 4 + r;
                int bb = m >> 11, t = m & (T_ - 1);
                VT[(((size_t)bb * H_ + h) * D_ + d) * T_ + t] =
                    (short)f2b(acc[mi][nj][r] + bv);
            }
        }
    }
}

// ---------------------------------------------------------------------------
// proj: out fp32 [M,C] = Yb(bf16) @ WpT(bf16) + bias. 64x128 tile, XCD
// remap, BK=64 panels, LDS 24 KB. (R24)
// ---------------------------------------------------------------------------
__global__ __launch_bounds__(256, 4) void proj_mfma(
    const short* __restrict__ Ah, const short* __restrict__ BTh,
    const float* __restrict__ bias, float* __restrict__ out)
{
    __shared__ short Ash[2][64 * 32];
    __shared__ short Bsh[2][128 * 32];

    const int tid  = threadIdx.x;
    const int wave = tid >> 6, lane = tid & 63;
    const int wm = wave >> 1, wn = wave & 1;
    const int lm = lane & 15, lq = lane >> 4;
    const int fid = blockIdx.y * 8 + blockIdx.x;
    const int wg  = (fid & 7) * 64 + (fid >> 3);
    const int n0  = (wg & 7) * 128;
    const int m0  = (wg >> 3) * 64;
    const int gr  = (lane >> 2);
    const int gc  = (((lane & 3) ^ ((lane >> 3) & 3)) << 3);
    const int sg  = ((lq ^ ((lm >> 1) & 3)) << 3);

    f32x4 acc[2][4] = {};

    for (int k0 = 0; k0 < C_; k0 += 64) {
        __syncthreads();
        #pragma unroll
        for (int p = 0; p < 2; p++) {
            int kp = k0 + p * 32;
            int rowA = wave * 16 + gr;
            gload_lds16(&Ah[(size_t)(m0 + rowA) * C_ + kp + gc], &Ash[p][wave * 512]);
            #pragma unroll
            for (int j = 0; j < 2; j++) {
                int s = wave * 2 + j;
                int rowB = s * 16 + gr;
                gload_lds16(&BTh[(size_t)(n0 + rowB) * C_ + kp + gc], &Bsh[p][s * 512]);
            }
        }
        __syncthreads();

        #pragma unroll
        for (int p = 0; p < 2; p++) {
            s16x8 af[2], bfr[4];
            #pragma unroll
            for (int mi = 0; mi < 2; mi++)
                af[mi] = *(const s16x8*)&Ash[p][(wm * 32 + mi * 16 + lm) * 32 + sg];
            #pragma unroll
            for (int nj = 0; nj < 4; nj++)
                bfr[nj] = *(const s16x8*)&Bsh[p][(wn * 64 + nj * 16 + lm) * 32 + sg];
            #pragma unroll
            for (int mi = 0; mi < 2; mi++)
                #pragma unroll
                for (int nj = 0; nj < 4; nj++)
                    acc[mi][nj] = MFMA16(af[mi], bfr[nj], acc[mi][nj]);
        }
    }

    #pragma unroll
    for (int nj = 0; nj < 4; nj++) {
        int n = n0 + wn * 64 + nj * 16 + lm;
        float bv = bias[n];
        #pragma unroll
        for (int mi = 0; mi < 2; mi++) {
            #pragma unroll
            for (int r = 0; r < 4; r++) {
                int m = m0 + wm * 32 + mi * 16 + lq * 4 + r;
                out[(size_t)m * C_ + n] = acc[mi][nj][r] + bv;
            }
        }
    }
}

// ---------------------------------------------------------------------------
// online softmax over 32 S-values (8 frags), exp2 domain, defer-max THR=8.
// On exit S holds P = exp2(S - m). Low-pressure tree (8 temps).
// ---------------------------------------------------------------------------
__device__ __forceinline__ void online_sm8(
    f32x4 S[8], float& mrow, float& lrow, f32x4 O[4], int quad)
{
    float a[8];
    #pragma unroll
    for (int t = 0; t < 8; t++)
        a[t] = fmaxf(fmaxf(S[t][0], S[t][1]), fmaxf(S[t][2], S[t][3]));
    #pragma unroll
    for (int s = 4; s; s >>= 1)
        #pragma unroll
        for (int i = 0; i < s; i++) a[i] = fmaxf(a[i], a[i + s]);
    float rm = a[0];
    rm = fmaxf(rm, __shfl_xor(rm, 16, 64));
    rm = fmaxf(rm, __shfl_xor(rm, 32, 64));
    // defer-max: only rescale when some row grew by > 8 (=2^8 headroom)
    if (!__all(rm - mrow <= 8.f)) {
        float mnew  = fmaxf(mrow, rm);
        float alpha = fexp2(mrow - mnew);
        mrow = mnew;
        lrow *= alpha;
        float al[4];
        #pragma unroll
        for (int r = 0; r < 4; r++) al[r] = __shfl(alpha, quad * 4 + r, 64);
        #pragma unroll
        for (int t = 0; t < 4; t++)
            #pragma unroll
            for (int r = 0; r < 4; r++) O[t][r] *= al[r];
    }
    float sv[8];
    #pragma unroll
    for (int t = 0; t < 8; t++) {
        #pragma unroll
        for (int r = 0; r < 4; r++) S[t][r] = fexp2(S[t][r] - mrow);
        sv[t] = (S[t][0] + S[t][1]) + (S[t][2] + S[t][3]);
    }
    #pragma unroll
    for (int s = 4; s; s >>= 1)
        #pragma unroll
        for (int i = 0; i < s; i++) sv[i] += sv[i + s];
    float rs = sv[0];
    rs += __shfl_xor(rs, 16, 64);
    rs += __shfl_xor(rs, 32, 64);
    lrow += rs;
}

// ---------------------------------------------------------------------------
// MFMA flash attention, S^T layout, PAIRED q-tiles, KVBLK=128. Grid 512.
// Block: qtA=j, qtB=31-j of one (b,h). 17 chunk-iterations per block
// (exact, all j); dual-chain while c <= j>>1 (9 dual/CU slot, balanced).
// Diagonal mask at chunk c==qt>>1: key-in-chunk > (qt&1)*64 + qg.
// LDS 80KB XOR-swizzled, 2 blocks/CU. exp2-domain defer-max softmax.
// ---------------------------------------------------------------------------
__global__ __launch_bounds__(256, 2) void attn_mfma(
    const short* __restrict__ Qh, const short* __restrict__ Ql,
    const short* __restrict__ Kh, const short* __restrict__ Kl,
    const short* __restrict__ VT, short* __restrict__ Yb)
{
    __shared__ short Ksh[128][64], Ksl[128][64];  // [key][d], XOR-swizzled
    __shared__ short Vt [64][128];                // [d][key], XOR-swizzled
    __shared__ short Ps [4][2][16][128];          // per-wave P slabs (B=0,A=1)

    const int tid  = threadIdx.x;
    const int wave = tid >> 6, lane = tid & 63;
    const int lm   = lane & 15, quad = lane >> 4;
    const int swz  = (lm & 7) << 3;              // read-side XOR (shorts)

    const int bid = blockIdx.x;                  // 512 blocks
    const int xcd = bid & 7;
    const int r_  = bid >> 3;                    // 0..63 per XCD
    const int bhl = r_ & 3;
    const int u   = r_ >> 2;                     // 0..15
    const int g_  = u >> 3, j_ = u & 7;
    const int j   = g_ ? (15 - j_) : j_;         // CU slot pairs j with 15-j
    const int bh  = xcd * 4 + bhl;
    const int b   = bh >> 4, h = bh & (H_ - 1);
    const int qtA = j, qtB = 31 - j;
    const int q0A = qtA * 64, q0B = qtB * 64;
    const int cA  = qtA >> 1, cB = qtB >> 1;     // diagonal chunk per tile
    const int thrA = (qtA & 1) << 6;             // diag threshold offsets
    const int thrB = (qtB & 1) << 6;
    const size_t base  = (size_t)bh * T_ * D_;   // Q,K: [b,h,t,d]
    const size_t vbase = (size_t)bh * D_ * T_;   // VT:  [b,h,d,t]

    // ---- Q frags direct from global (L2-hit, once per block) ----
    s16x8 bqhA[2], bqlA[2], bqhB[2], bqlB[2];
    #pragma unroll
    for (int kc = 0; kc < 2; kc++) {
        size_t ga = base + (size_t)(q0A + wave * 16 + lm) * D_ + kc * 32 + quad * 8;
        size_t gb = base + (size_t)(q0B + wave * 16 + lm) * D_ + kc * 32 + quad * 8;
        bqhA[kc] = *(const s16x8*)&Qh[ga];
        bqlA[kc] = *(const s16x8*)&Ql[ga];
        bqhB[kc] = *(const s16x8*)&Qh[gb];
        bqlB[kc] = *(const s16x8*)&Ql[gb];
    }

    // ---- prefetch chunk 0 (128 K-rows, 64 Vt-rows x 128 keys) ----
    s16x8 pkh[4], pkl[4], pvt[4];
    #pragma unroll
    for (int i = 0; i < 4; i++) {
        int g  = i * 256 + tid;
        int rk = g >> 3, ck = (g & 7) * 8;
        size_t gk = base + (size_t)rk * D_ + ck;
        pkh[i] = *(const s16x8*)&Kh[gk];
        pkl[i] = *(const s16x8*)&Kl[gk];
        int rv = g >> 4, cv = (g & 15) * 8;
        pvt[i] = *(const s16x8*)&VT[vbase + (size_t)rv * T_ + cv];
    }

    float mA = -INFINITY, lA = 0.f;
    float mB = -INFINITY, lB = 0.f;
    f32x4 OA[4] = {}, OB[4] = {};

    for (int c = 0; c <= cB; c++) {
        __syncthreads();                          // prev chunk's readers done
        #pragma unroll
        for (int i = 0; i < 4; i++) {             // VGPR -> LDS (swizzled)
            int g  = i * 256 + tid;
            int rk = g >> 3;
            int wK = ((g & 7) * 8) ^ ((rk & 7) << 3);
            *(s16x8*)&Ksh[rk][wK] = pkh[i];
            *(s16x8*)&Ksl[rk][wK] = pkl[i];
            int rv = g >> 4;
            int wV = ((g & 15) * 8) ^ ((rv & 7) << 3);
            *(s16x8*)&Vt[rv][wV] = pvt[i];
        }
        if (c < cB) {                             // issue next chunk's loads
            #pragma unroll
            for (int i = 0; i < 4; i++) {
                int g  = i * 256 + tid;
                int rk = g >> 3, ck = (g & 7) * 8;
                size_t gk = base + (size_t)((c + 1) * 128 + rk) * D_ + ck;
                pkh[i] = *(const s16x8*)&Kh[gk];
                pkl[i] = *(const s16x8*)&Kl[gk];
                int rv = g >> 4, cv = (g & 15) * 8;
                pvt[i] = *(const s16x8*)&VT[vbase + (size_t)rv * T_ + (c + 1) * 128 + cv];
            }
        }
        __syncthreads();

        const bool doA = (c <= cA);
        const int  qg  = wave * 16 + lm;

        // ---- S^T = K Q^T (bf16x3) over 128 keys ----
        f32x4 SB[8] = {}, SA[8] = {};
        if (doA) {
            #pragma unroll
            for (int t = 0; t < 8; t++)
                #pragma unroll
                for (int kc = 0; kc < 2; kc++) {
                    s16x8 kh8 = *(const s16x8*)&Ksh[t * 16 + lm][(kc * 32 + quad * 8) ^ swz];
                    s16x8 kl8 = *(const s16x8*)&Ksl[t * 16 + lm][(kc * 32 + quad * 8) ^ swz];
                    SB[t] = MFMA16(kh8, bqhB[kc], SB[t]);
                    SB[t] = MFMA16(kl8, bqhB[kc], SB[t]);
                    SB[t] = MFMA16(kh8, bqlB[kc], SB[t]);
                    SA[t] = MFMA16(kh8, bqhA[kc], SA[t]);
                    SA[t] = MFMA16(kl8, bqhA[kc], SA[t]);
                    SA[t] = MFMA16(kh8, bqlA[kc], SA[t]);
                }
        } else {
            #pragma unroll
            for (int t = 0; t < 8; t++)
                #pragma unroll
                for (int kc = 0; kc < 2; kc++) {
                    s16x8 kh8 = *(const s16x8*)&Ksh[t * 16 + lm][(kc * 32 + quad * 8) ^ swz];
                    s16x8 kl8 = *(const s16x8*)&Ksl[t * 16 + lm][(kc * 32 + quad * 8) ^ swz];
                    SB[t] = MFMA16(kh8, bqhB[kc], SB[t]);
                    SB[t] = MFMA16(kl8, bqhB[kc], SB[t]);
                    SB[t] = MFMA16(kh8, bqlB[kc], SB[t]);
                }
        }

        // causal masks at diagonal chunks (scale pre-folded into Q)
        if (c == cB) {
            #pragma unroll
            for (int t = 0; t < 8; t++)
                #pragma unroll
                for (int r = 0; r < 4; r++)
                    if ((t * 16 + quad * 4 + r) > thrB + qg) SB[t][r] = -INFINITY;
        }
        if (c == cA) {
            #pragma unroll
            for (int t = 0; t < 8; t++)
                #pragma unroll
                for (int r = 0; r < 4; r++)
                    if ((t * 16 + quad * 4 + r) > thrA + qg) SA[t][r] = -INFINITY;
        }

        // ---- softmax (dual chains independent) ----
        online_sm8(SB, mB, lB, OB, quad);
        if (doA) online_sm8(SA, mA, lA, OA, quad);

        // ---- P^T -> Ps (truncating bf16; P in [0, 256]) ----
        #pragma unroll
        for (int t = 0; t < 8; t++) {
            s16x4 p;
            #pragma unroll
            for (int r = 0; r < 4; r++)
                p[r] = (short)(__float_as_uint(SB[t][r]) >> 16);
            *(s16x4*)&Ps[wave][0][lm][(t * 16 + quad * 4) ^ swz] = p;
        }
        if (doA) {
            #pragma unroll
            for (int t = 0; t < 8; t++) {
                s16x4 p;
                #pragma unroll
                for (int r = 0; r < 4; r++)
                    p[r] = (short)(__float_as_uint(SA[t][r]) >> 16);
                *(s16x4*)&Ps[wave][1][lm][(t * 16 + quad * 4) ^ swz] = p;
            }
        }
        // wave-private slabs: no barrier (lgkmcnt ordering within wave)

        // ---- O += P V over 128 keys: shared Vt frags feed both tiles ----
        s16x8 apB[4], apA[4];
        #pragma unroll
        for (int kc = 0; kc < 4; kc++)
            apB[kc] = *(const s16x8*)&Ps[wave][0][lm][(kc * 32 + quad * 8) ^ swz];
        if (doA) {
            #pragma unroll
            for (int kc = 0; kc < 4; kc++)
                apA[kc] = *(const s16x8*)&Ps[wave][1][lm][(kc * 32 + quad * 8) ^ swz];
            #pragma unroll
            for (int t = 0; t < 4; t++)
                #pragma unroll
                for (int kc = 0; kc < 4; kc++) {
                    s16x8 bv = *(const s16x8*)&Vt[t * 16 + lm][(kc * 32 + quad * 8) ^ swz];
                    OB[t] = MFMA16(apB[kc], bv, OB[t]);
                    OA[t] = MFMA16(apA[kc], bv, OA[t]);
                }
        } else {
            #pragma unroll
            for (int t = 0; t < 4; t++)
                #pragma unroll
                for (int kc = 0; kc < 4; kc++) {
                    s16x8 bv = *(const s16x8*)&Vt[t * 16 + lm][(kc * 32 + quad * 8) ^ swz];
                    OB[t] = MFMA16(apB[kc], bv, OB[t]);
                }
        }
    }

    // ---- epilogue: O row q = wave*16+quad*4+r, col d = t*16+lm ----
    float liA[4], liB[4];
    #pragma unroll
    for (int r = 0; r < 4; r++) {
        liA[r] = 1.0f / __shfl(lA, quad * 4 + r, 64);
        liB[r] = 1.0f / __shfl(lB, quad * 4 + r, 64);
    }
    #pragma unroll
    for (int t = 0; t < 4; t++)
        #pragma unroll
        for (int r = 0; r < 4; r++) {
            int d  = t * 16 + lm;
            int qa = q0A + wave * 16 + quad * 4 + r;
            int qb = q0B + wave * 16 + quad * 4 + r;
            Yb[((size_t)b * T_ + qa) * C_ + h * D_ + d] =
                (short)f2b(OA[t][r] * liA[r]);
            Yb[((size_t)b * T_ + qb) * C_ + h * D_ + d] =
                (short)f2b(OB[t][r] * liB[r]);
        }
}

// ---------------------------------------------------------------------------
extern "C" void kernel_launch(void* const* d_in, const int* in_sizes, int n_in,
                              void* d_out, int out_size, void* d_ws, size_t ws_size,
                              hipStream_t stream)
{
    const float* x      = (const float*)d_in[0];
    const float* W_attn = (const float*)d_in[1];
    const float* b_attn = (const float*)d_in[2];
    const float* W_proj = (const float*)d_in[3];
    const float* b_proj = (const float*)d_in[4];
    float* out = (float*)d_out;

    char* ws = (char*)d_ws;
    const size_t MB = 1024 * 1024;
    short* Qh   = (short*)(ws);            // 8 MB  [ 0, 8)
    short* Ql   = (short*)(ws +  8 * MB);  // 8 MB  [ 8,16)
    short* Kh   = (short*)(ws + 16 * MB);  // 8 MB  [16,24)
    short* Kl   = (short*)(ws + 24 * MB);  // 8 MB  [24,32)
    short* xh   = (short*)(ws + 32 * MB);  // 8 MB  [32,40)  dead after qkv_v
    short* xl   = (short*)(ws + 40 * MB);  // 8 MB  [40,48)  dead after qkv_qk
    short* WaTh = (short*)(ws + 48 * MB);  // 6 MB  [48,54)
    short* WaTl = (short*)(ws + 54 * MB);  // 6 MB  [54,60)
    short* WpT  = (short*)(ws + 60 * MB);  // 2 MB  [60,62)
    short* VT   = (short*)(ws + 40 * MB);  // 8 MB  aliases xl (born at qkv_v)
    short* Yb   = (short*)(ws + 32 * MB);  // 8 MB  aliases xh (born at attn)

    cvt_all<<<dim3(3072), 256, 0, stream>>>(x, xh, xl, W_attn, WaTh, WaTl,
                                            W_proj, WpT);

    qkv_qk <<<dim3(16, 32), 256, 0, stream>>>(xh, xl, WaTh, WaTl, b_attn,
                                              Qh, Ql, Kh, Kl);
    qkv_v  <<<dim3(8, 64), 256, 0, stream>>>(xh, WaTh + (size_t)2048 * C_,
                                             b_attn + 2048, VT);
    attn_mfma<<<dim3(512), 256, 0, stream>>>(Qh, Ql, Kh, Kl, VT, Yb);
    proj_mfma<<<dim3(8, 64), 256, 0, stream>>>(Yb, WpT, b_proj, out);
}

// Round 14
// 235.640 us; speedup vs baseline: 1.0472x; 1.0472x over previous
//
#include <hip/hip_runtime.h>
#include <hip/hip_bf16.h>

// Problem: CausalSelfAttention  B=2, T=2048, C=1024, H=16, D=64
// Round 26: revert KVBLK=128 (R25: attn 61->74, VGPR blowup + Vt conflicts,
// kill-rule fired) -> KVBLK=64 R17-exact attn body. Base = R24-measured
// config (cvt_all | BK=64 XCD 0-conflict GEMMs | paired attn). ONE isolated
// change: T5 s_setprio(1/0) around attn's QK and PV MFMA clusters only
// (catalog m191: +4-7% on attn w/ wave-phase diversity; GEMMs lockstep ->
// left alone, m190 null). Numerics byte-identical.
// ws (62 MB): Qh 8|Ql 8|Kh 8|Kl 8|xh 8(->Yb)|xl 8(->VT)|WaTh 6|WaTl 6|WpT 2

#define B_  2
#define T_  2048
#define C_  1024
#define H_  16
#define D_  64
#define M_  (B_ * T_)      // 4096
#define N3_ (3 * C_)       // 3072

typedef __attribute__((ext_vector_type(8))) short s16x8;
typedef __attribute__((ext_vector_type(4))) short s16x4;
typedef __attribute__((ext_vector_type(4))) float f32x4;

typedef const __attribute__((address_space(1))) unsigned int gu32_t;
typedef __attribute__((address_space(3))) unsigned int lu32_t;

#define MFMA16(a, b, c) __builtin_amdgcn_mfma_f32_16x16x32_bf16(a, b, c, 0, 0, 0)

__device__ __forceinline__ void gload_lds16(const short* g, short* l) {
    __builtin_amdgcn_global_load_lds((gu32_t*)g, (lu32_t*)l, 16, 0, 0);
}

__device__ __forceinline__ float b2f(unsigned short u) {
    return __uint_as_float(((unsigned)u) << 16);
}
__device__ __forceinline__ unsigned short f2b(float f) {   // RNE bf16 round
    unsigned u = __float_as_uint(f);
    return (unsigned short)((u + 0x7FFFu + ((u >> 16) & 1u)) >> 16);
}
__device__ __forceinline__ float fexp2(float x) {
#if __has_builtin(__builtin_amdgcn_exp2f)
    return __builtin_amdgcn_exp2f(x);
#else
    return exp2f(x);
#endif
}

// ---------------------------------------------------------------------------
// cvt_all: one dispatch for all input conversions (grid 3072).
// ---------------------------------------------------------------------------
__global__ __launch_bounds__(256) void cvt_all(
    const float* __restrict__ x,  short* __restrict__ xh,   short* __restrict__ xl,
    const float* __restrict__ Wa, short* __restrict__ WaTh, short* __restrict__ WaTl,
    const float* __restrict__ Wp, short* __restrict__ WpT)
{
    __shared__ short th[64][80];
    __shared__ short tl[64][80];
    const int tid = threadIdx.x;
    const int bid = blockIdx.x;

    if (bid < 2048) {
        int i = (bid * 256 + tid) * 8;
        float4 a = *(const float4*)&x[i];
        float4 b = *(const float4*)&x[i + 4];
        float v[8] = {a.x, a.y, a.z, a.w, b.x, b.y, b.z, b.w};
        s16x8 h, l;
        #pragma unroll
        for (int j = 0; j < 8; j++) {
            unsigned short hb = f2b(v[j]);
            h[j] = (short)hb;
            l[j] = (short)f2b(v[j] - b2f(hb));
        }
        *(s16x8*)&xh[i] = h;
        *(s16x8*)&xl[i] = l;
        return;
    }

    if (bid < 2816) {
        int r  = bid - 2048;            // 0..767
        int bx = r % 48, by = r / 48;   // (N3_/64, C_/64)
        const int k0 = by * 64, n0 = bx * 64;
        const int R = C_, Cn = N3_;
        {
            int rl = tid >> 4, cl = (tid & 15) * 4;
            #pragma unroll
            for (int i = 0; i < 4; i++) {
                int kr = rl + i * 16;
                float4 v4 = *(const float4*)&Wa[(size_t)(k0 + kr) * Cn + n0 + cl];
                float v[4] = {v4.x, v4.y, v4.z, v4.w};
                #pragma unroll
                for (int j = 0; j < 4; j++) {
                    unsigned short hb = f2b(v[j]);
                    th[cl + j][kr] = (short)hb;
                    tl[cl + j][kr] = (short)f2b(v[j] - b2f(hb));
                }
            }
        }
        __syncthreads();
        {
            int ro = tid >> 2, co = (tid & 3) * 16;
            *(s16x8*)&WaTh[(size_t)(n0 + ro) * R + k0 + co]     = *(s16x8*)&th[ro][co];
            *(s16x8*)&WaTh[(size_t)(n0 + ro) * R + k0 + co + 8] = *(s16x8*)&th[ro][co + 8];
            *(s16x8*)&WaTl[(size_t)(n0 + ro) * R + k0 + co]     = *(s16x8*)&tl[ro][co];
            *(s16x8*)&WaTl[(size_t)(n0 + ro) * R + k0 + co + 8] = *(s16x8*)&tl[ro][co + 8];
        }
        return;
    }

    {
        int r  = bid - 2816;            // 0..255
        int bx = r & 15, by = r >> 4;   // (C_/64, C_/64)
        const int k0 = by * 64, n0 = bx * 64;
        const int R = C_, Cn = C_;
        {
            int rl = tid >> 4, cl = (tid & 15) * 4;
            #pragma unroll
            for (int i = 0; i < 4; i++) {
                int kr = rl + i * 16;
                float4 v = *(const float4*)&Wp[(size_t)(k0 + kr) * Cn + n0 + cl];
                th[cl + 0][kr] = (short)f2b(v.x);
                th[cl + 1][kr] = (short)f2b(v.y);
                th[cl + 2][kr] = (short)f2b(v.z);
                th[cl + 3][kr] = (short)f2b(v.w);
            }
        }
        __syncthreads();
        {
            int ro = tid >> 2, co = (tid & 3) * 16;
            *(s16x8*)&WpT[(size_t)(n0 + ro) * R + k0 + co]     = *(s16x8*)&th[ro][co];
            *(s16x8*)&WpT[(size_t)(n0 + ro) * R + k0 + co + 8] = *(s16x8*)&th[ro][co + 8];
        }
    }
}

// ---------------------------------------------------------------------------
// qkv_qk: Q,K columns (N=2048), bf16x3, hi/lo scatter. 128x128 tile, XCD
// remap, BK=64 panels, LDS 64 KB, 0-conflict granule swizzle. (R24, 61.2us)
// ---------------------------------------------------------------------------
__global__ __launch_bounds__(256) void qkv_qk(
    const short* __restrict__ Ah, const short* __restrict__ Al,
    const short* __restrict__ BTh, const short* __restrict__ BTl,
    const float* __restrict__ bias,
    short* __restrict__ Qh, short* __restrict__ Ql,
    short* __restrict__ Kh, short* __restrict__ Kl)
{
    __shared__ short Ash[2][128 * 32], Asl[2][128 * 32];
    __shared__ short Bsh[2][128 * 32], Bsl[2][128 * 32];   // 64 KB

    const int tid  = threadIdx.x;
    const int wave = tid >> 6, lane = tid & 63;
    const int wm = wave >> 1, wn = wave & 1;
    const int lm = lane & 15, lq = lane >> 4;
    const int fid = blockIdx.y * 16 + blockIdx.x;
    const int wg  = (fid & 7) * 64 + (fid >> 3);
    const int n0  = (wg & 15) * 128;
    const int m0  = (wg >> 4) * 128;
    const int gr  = (lane >> 2);
    const int gc  = (((lane & 3) ^ ((lane >> 3) & 3)) << 3);
    const int sg  = ((lq ^ ((lm >> 1) & 3)) << 3);

    f32x4 acc[4][4] = {};

    for (int k0 = 0; k0 < C_; k0 += 64) {
        __syncthreads();
        #pragma unroll
        for (int p = 0; p < 2; p++) {
            int kp = k0 + p * 32;
            #pragma unroll
            for (int j = 0; j < 2; j++) {
                int s = wave * 2 + j;
                int row = s * 16 + gr;
                size_t ga = (size_t)(m0 + row) * C_ + kp + gc;
                size_t gb = (size_t)(n0 + row) * C_ + kp + gc;
                gload_lds16(&Ah[ga],  &Ash[p][s * 512]);
                gload_lds16(&Al[ga],  &Asl[p][s * 512]);
                gload_lds16(&BTh[gb], &Bsh[p][s * 512]);
                gload_lds16(&BTl[gb], &Bsl[p][s * 512]);
            }
        }
        __syncthreads();

        #pragma unroll
        for (int p = 0; p < 2; p++) {
            s16x8 ah[4], al[4], bh[4], bl[4];
            #pragma unroll
            for (int mi = 0; mi < 4; mi++) {
                int r = wm * 64 + mi * 16 + lm;
                ah[mi] = *(const s16x8*)&Ash[p][r * 32 + sg];
                al[mi] = *(const s16x8*)&Asl[p][r * 32 + sg];
            }
            #pragma unroll
            for (int nj = 0; nj < 4; nj++) {
                int r = wn * 64 + nj * 16 + lm;
                bh[nj] = *(const s16x8*)&Bsh[p][r * 32 + sg];
                bl[nj] = *(const s16x8*)&Bsl[p][r * 32 + sg];
            }
            #pragma unroll
            for (int mi = 0; mi < 4; mi++)
                #pragma unroll
                for (int nj = 0; nj < 4; nj++) {
                    acc[mi][nj] = MFMA16(ah[mi], bh[nj], acc[mi][nj]);
                    acc[mi][nj] = MFMA16(ah[mi], bl[nj], acc[mi][nj]);
                    acc[mi][nj] = MFMA16(al[mi], bh[nj], acc[mi][nj]);
                }
        }
    }

    #pragma unroll
    for (int nj = 0; nj < 4; nj++) {
        int n = n0 + wn * 64 + nj * 16 + lm;
        float bv = bias[n];
        int isK = n >> 10;
        int c = n & (C_ - 1);
        int h = c >> 6, d = c & (D_ - 1);
        short* dh = isK ? Kh : Qh;
        short* dl = isK ? Kl : Ql;
        // Q carries sqrt(D)=8 and log2(e): softmax runs in exp2 domain
        float scale = isK ? 1.0f : 11.541560327111708f;   // 8*log2(e)
        #pragma unroll
        for (int mi = 0; mi < 4; mi++) {
            #pragma unroll
            for (int r = 0; r < 4; r++) {
                int m  = m0 + wm * 64 + mi * 16 + lq * 4 + r;
                int bb = m >> 11, t = m & (T_ - 1);
                float v = (acc[mi][nj][r] + bv) * scale;
                size_t idx = (((size_t)bb * H_ + h) * T_ + t) * D_ + d;
                unsigned short hb = f2b(v);
                dh[idx] = (short)hb;
                dl[idx] = (short)f2b(v - b2f(hb));
            }
        }
    }
}

// ---------------------------------------------------------------------------
// qkv_v: V columns (N=1024), single bf16, scatter TRANSPOSED -> VT [B,H,D,T].
// 64x128 tile, XCD remap, BK=64 panels, LDS 24 KB. (R24)
// ---------------------------------------------------------------------------
__global__ __launch_bounds__(256, 4) void qkv_v(
    const short* __restrict__ Ah, const short* __restrict__ BTh,
    const float* __restrict__ bias, short* __restrict__ VT)
{
    __shared__ short Ash[2][64 * 32];    // 8 KB
    __shared__ short Bsh[2][128 * 32];   // 16 KB

    const int tid  = threadIdx.x;
    const int wave = tid >> 6, lane = tid & 63;
    const int wm = wave >> 1, wn = wave & 1;
    const int lm = lane & 15, lq = lane >> 4;
    const int fid = blockIdx.y * 8 + blockIdx.x;
    const int wg  = (fid & 7) * 64 + (fid >> 3);
    const int n0  = (wg & 7) * 128;
    const int m0  = (wg >> 3) * 64;
    const int gr  = (lane >> 2);
    const int gc  = (((lane & 3) ^ ((lane >> 3) & 3)) << 3);
    const int sg  = ((lq ^ ((lm >> 1) & 3)) << 3);

    f32x4 acc[2][4] = {};

    for (int k0 = 0; k0 < C_; k0 += 64) {
        __syncthreads();
        #pragma unroll
        for (int p = 0; p < 2; p++) {
            int kp = k0 + p * 32;
            int rowA = wave * 16 + gr;
            gload_lds16(&Ah[(size_t)(m0 + rowA) * C_ + kp + gc], &Ash[p][wave * 512]);
            #pragma unroll
            for (int j = 0; j < 2; j++) {
                int s = wave * 2 + j;
                int rowB = s * 16 + gr;
                gload_lds16(&BTh[(size_t)(n0 + rowB) * C_ + kp + gc], &Bsh[p][s * 512]);
            }
        }
        __syncthreads();

        #pragma unroll
        for (int p = 0; p < 2; p++) {
            s16x8 af[2], bfr[4];
            #pragma unroll
            for (int mi = 0; mi < 2; mi++)
                af[mi] = *(const s16x8*)&Ash[p][(wm * 32 + mi * 16 + lm) * 32 + sg];
            #pragma unroll
            for (int nj = 0; nj < 4; nj++)
                bfr[nj] = *(const s16x8*)&Bsh[p][(wn * 64 + nj * 16 + lm) * 32 + sg];
            #pragma unroll
            for (int mi = 0; mi < 2; mi++)
                #pragma unroll
                for (int nj = 0; nj < 4; nj++)
                    acc[mi][nj] = MFMA16(af[mi], bfr[nj], acc[mi][nj]);
        }
    }

    #pragma unroll
    for (int nj = 0; nj < 4; nj++) {
        int n = n0 + wn * 64 + nj * 16 + lm;    // [0, 1024) V channel
        float bv = bias[n];
        int h = n >> 6, d = n & (D_ - 1);
        #pragma unroll
        for (int mi = 0; mi < 2; mi++) {
            #pragma unroll
            for (int r = 0; r < 4; r++) {
                int m  = m0 + wm * 32 + mi * 16 + lq * 4 + r;
                int bb = m >> 11, t = m & (T_ - 1);
                VT[(((size_t)bb * H_ + h) * D_ + d) * T_ + t] =
                    (short)f2b(acc[mi][nj][r] + bv);
            }
        }
    }
}

// ---------------------------------------------------------------------------
// proj: out fp32 [M,C] = Yb(bf16) @ WpT(bf16) + bias. 64x128 tile, XCD
// remap, BK=64 panels, LDS 24 KB. (R24)
// ---------------------------------------------------------------------------
__global__ __launch_bounds__(256, 4) void proj_mfma(
    const short* __restrict__ Ah, const short* __restrict__ BTh,
    const float* __restrict__ bias, float* __restrict__ out)
{
    __shared__ short Ash[2][64 * 32];
    __shared__ short Bsh[2][128 * 32];

    const int tid  = threadIdx.x;
    const int wave = tid >> 6, lane = tid & 63;
    const int wm = wave >> 1, wn = wave & 1;
    const int lm = lane & 15, lq = lane >> 4;
    const int fid = blockIdx.y * 8 + blockIdx.x;
    const int wg  = (fid & 7) * 64 + (fid >> 3);
    const int n0  = (wg & 7) * 128;
    const int m0  = (wg >> 3) * 64;
    const int gr  = (lane >> 2);
    const int gc  = (((lane & 3) ^ ((lane >> 3) & 3)) << 3);
    const int sg  = ((lq ^ ((lm >> 1) & 3)) << 3);

    f32x4 acc[2][4] = {};

    for (int k0 = 0; k0 < C_; k0 += 64) {
        __syncthreads();
        #pragma unroll
        for (int p = 0; p < 2; p++) {
            int kp = k0 + p * 32;
            int rowA = wave * 16 + gr;
            gload_lds16(&Ah[(size_t)(m0 + rowA) * C_ + kp + gc], &Ash[p][wave * 512]);
            #pragma unroll
            for (int j = 0; j < 2; j++) {
                int s = wave * 2 + j;
                int rowB = s * 16 + gr;
                gload_lds16(&BTh[(size_t)(n0 + rowB) * C_ + kp + gc], &Bsh[p][s * 512]);
            }
        }
        __syncthreads();

        #pragma unroll
        for (int p = 0; p < 2; p++) {
            s16x8 af[2], bfr[4];
            #pragma unroll
            for (int mi = 0; mi < 2; mi++)
                af[mi] = *(const s16x8*)&Ash[p][(wm * 32 + mi * 16 + lm) * 32 + sg];
            #pragma unroll
            for (int nj = 0; nj < 4; nj++)
                bfr[nj] = *(const s16x8*)&Bsh[p][(wn * 64 + nj * 16 + lm) * 32 + sg];
            #pragma unroll
            for (int mi = 0; mi < 2; mi++)
                #pragma unroll
                for (int nj = 0; nj < 4; nj++)
                    acc[mi][nj] = MFMA16(af[mi], bfr[nj], acc[mi][nj]);
        }
    }

    #pragma unroll
    for (int nj = 0; nj < 4; nj++) {
        int n = n0 + wn * 64 + nj * 16 + lm;
        float bv = bias[n];
        #pragma unroll
        for (int mi = 0; mi < 2; mi++) {
            #pragma unroll
            for (int r = 0; r < 4; r++) {
                int m = m0 + wm * 32 + mi * 16 + lq * 4 + r;
                out[(size_t)m * C_ + n] = acc[mi][nj][r] + bv;
            }
        }
    }
}

// ---------------------------------------------------------------------------
// online softmax (exp2 domain) with defer-max (THR=8). S in/out: S^T frag,
// per-thread 16 values for q-row lm. On exit S holds P = exp2(S - m).
// ---------------------------------------------------------------------------
__device__ __forceinline__ void online_sm(
    f32x4 S[4], float& mrow, float& lrow, f32x4 O[4], int quad)
{
    float v[16];
    #pragma unroll
    for (int t = 0; t < 4; t++)
        #pragma unroll
        for (int r = 0; r < 4; r++) v[t * 4 + r] = S[t][r];
    #pragma unroll
    for (int s = 8; s; s >>= 1)
        #pragma unroll
        for (int i = 0; i < s; i++) v[i] = fmaxf(v[i], v[i + s]);
    float rm = v[0];
    rm = fmaxf(rm, __shfl_xor(rm, 16, 64));
    rm = fmaxf(rm, __shfl_xor(rm, 32, 64));
    // defer-max: only rescale when some row grew by > 8 (=2^8 headroom)
    if (!__all(rm - mrow <= 8.f)) {
        float mnew  = fmaxf(mrow, rm);
        float alpha = fexp2(mrow - mnew);
        mrow = mnew;
        lrow *= alpha;
        float al[4];
        #pragma unroll
        for (int r = 0; r < 4; r++) al[r] = __shfl(alpha, quad * 4 + r, 64);
        #pragma unroll
        for (int t = 0; t < 4; t++)
            #pragma unroll
            for (int r = 0; r < 4; r++) O[t][r] *= al[r];
    }
    float sv[16];
    #pragma unroll
    for (int t = 0; t < 4; t++)
        #pragma unroll
        for (int r = 0; r < 4; r++) {
            float p = fexp2(S[t][r] - mrow);
            S[t][r] = p;
            sv[t * 4 + r] = p;
        }
    #pragma unroll
    for (int s = 8; s; s >>= 1)
        #pragma unroll
        for (int i = 0; i < s; i++) sv[i] += sv[i + s];
    float rs = sv[0];
    rs += __shfl_xor(rs, 16, 64);
    rs += __shfl_xor(rs, 32, 64);
    lrow += rs;
}

// ---------------------------------------------------------------------------
// MFMA flash attention, S^T layout, PAIRED q-tiles per block. Grid 512.
// R17-exact structure + T5 setprio around the two MFMA clusters.
// LDS 40KB XOR-swizzled, 2 blocks/CU, exp2-domain defer-max softmax.
// ---------------------------------------------------------------------------
__global__ __launch_bounds__(256, 2) void attn_mfma(
    const short* __restrict__ Qh, const short* __restrict__ Ql,
    const short* __restrict__ Kh, const short* __restrict__ Kl,
    const short* __restrict__ VT, short* __restrict__ Yb)
{
    __shared__ short Ksh[64][64], Ksl[64][64];   // [key][d], XOR-swizzled
    __shared__ short Vt [64][64];                // [d][key], XOR-swizzled
    __shared__ short Ps [4][2][16][64];          // per-wave P slabs (B=0,A=1)

    const int tid  = threadIdx.x;
    const int wave = tid >> 6, lane = tid & 63;
    const int lm   = lane & 15, quad = lane >> 4;
    const int swz  = (lm & 7) << 3;              // read-side XOR (shorts)

    const int bid = blockIdx.x;                  // 512 blocks
    const int xcd = bid & 7;
    const int r_  = bid >> 3;                    // 0..63 per XCD
    const int bhl = r_ & 3;
    const int u   = r_ >> 2;                     // 0..15
    const int g_  = u >> 3, j_ = u & 7;
    const int j   = g_ ? (15 - j_) : j_;         // CU slot pairs j with 15-j
    const int bh  = xcd * 4 + bhl;
    const int b   = bh >> 4, h = bh & (H_ - 1);
    const int qtA = j, qtB = 31 - j;
    const int q0A = qtA * 64, q0B = qtB * 64;
    const size_t base  = (size_t)bh * T_ * D_;   // Q,K: [b,h,t,d]
    const size_t vbase = (size_t)bh * D_ * T_;   // VT:  [b,h,d,t]

    const int src = tid >> 3;                    // staging row 0..31 (+32)
    const int sch = (tid & 7) * 8;               // linear global col (shorts)
    const int wsw = sch ^ ((src & 7) << 3);      // swizzled LDS write col

    // ---- Q frags direct from global (L2-hit, once per block) ----
    s16x8 bqhA[2], bqlA[2], bqhB[2], bqlB[2];
    #pragma unroll
    for (int kc = 0; kc < 2; kc++) {
        size_t ga = base + (size_t)(q0A + wave * 16 + lm) * D_ + kc * 32 + quad * 8;
        size_t gb = base + (size_t)(q0B + wave * 16 + lm) * D_ + kc * 32 + quad * 8;
        bqhA[kc] = *(const s16x8*)&Qh[ga];
        bqlA[kc] = *(const s16x8*)&Ql[ga];
        bqhB[kc] = *(const s16x8*)&Qh[gb];
        bqlB[kc] = *(const s16x8*)&Ql[gb];
    }

    // ---- prefetch k-tile 0 into registers ----
    s16x8 pkh[2], pkl[2], pvt[2];
    #pragma unroll
    for (int i = 0; i < 2; i++) {
        int row = i * 32 + src;
        size_t gk = base + (size_t)row * D_ + sch;
        pkh[i] = *(const s16x8*)&Kh[gk];
        pkl[i] = *(const s16x8*)&Kl[gk];
        pvt[i] = *(const s16x8*)&VT[vbase + (size_t)row * T_ + sch];
    }

    float mA = -INFINITY, lA = 0.f;
    float mB = -INFINITY, lB = 0.f;
    f32x4 OA[4] = {}, OB[4] = {};

    for (int kt = 0; kt <= qtB; kt++) {
        __syncthreads();                          // prev tile's readers done
        #pragma unroll
        for (int i = 0; i < 2; i++) {             // VGPR -> LDS (swizzled)
            int row = i * 32 + src;
            *(s16x8*)&Ksh[row][wsw] = pkh[i];
            *(s16x8*)&Ksl[row][wsw] = pkl[i];
            *(s16x8*)&Vt [row][wsw] = pvt[i];
        }
        if (kt < qtB) {                           // issue next tile's loads
            #pragma unroll
            for (int i = 0; i < 2; i++) {
                int row = i * 32 + src;
                size_t gk = base + (size_t)((kt + 1) * 64 + row) * D_ + sch;
                pkh[i] = *(const s16x8*)&Kh[gk];
                pkl[i] = *(const s16x8*)&Kl[gk];
                pvt[i] = *(const s16x8*)&VT[vbase + (size_t)row * T_ + (kt + 1) * 64 + sch];
            }
        }
        __syncthreads();

        const bool doA = (kt <= qtA);
        const int  qg  = wave * 16 + lm;

        f32x4 SB[4] = {}, SA[4] = {};
        __builtin_amdgcn_s_setprio(1);
        if (doA) {
            // dual: one k-frag read feeds 6 MFMAs (two independent chains)
            #pragma unroll
            for (int t = 0; t < 4; t++)
                #pragma unroll
                for (int kc = 0; kc < 2; kc++) {
                    s16x8 kh8 = *(const s16x8*)&Ksh[t * 16 + lm][(kc * 32 + quad * 8) ^ swz];
                    s16x8 kl8 = *(const s16x8*)&Ksl[t * 16 + lm][(kc * 32 + quad * 8) ^ swz];
                    SB[t] = MFMA16(kh8, bqhB[kc], SB[t]);
                    SB[t] = MFMA16(kl8, bqhB[kc], SB[t]);
                    SB[t] = MFMA16(kh8, bqlB[kc], SB[t]);
                    SA[t] = MFMA16(kh8, bqhA[kc], SA[t]);
                    SA[t] = MFMA16(kl8, bqhA[kc], SA[t]);
                    SA[t] = MFMA16(kh8, bqlA[kc], SA[t]);
                }
        } else {
            #pragma unroll
            for (int t = 0; t < 4; t++)
                #pragma unroll
                for (int kc = 0; kc < 2; kc++) {
                    s16x8 kh8 = *(const s16x8*)&Ksh[t * 16 + lm][(kc * 32 + quad * 8) ^ swz];
                    s16x8 kl8 = *(const s16x8*)&Ksl[t * 16 + lm][(kc * 32 + quad * 8) ^ swz];
                    SB[t] = MFMA16(kh8, bqhB[kc], SB[t]);
                    SB[t] = MFMA16(kl8, bqhB[kc], SB[t]);
                    SB[t] = MFMA16(kh8, bqlB[kc], SB[t]);
                }
        }
        __builtin_amdgcn_s_setprio(0);

        // causal masks (scale pre-folded into Q)
        if (kt == qtB) {
            #pragma unroll
            for (int t = 0; t < 4; t++)
                #pragma unroll
                for (int r = 0; r < 4; r++)
                    if ((t * 16 + quad * 4 + r) > qg) SB[t][r] = -INFINITY;
        }
        if (kt == qtA) {
            #pragma unroll
            for (int t = 0; t < 4; t++)
                #pragma unroll
                for (int r = 0; r < 4; r++)
                    if ((t * 16 + quad * 4 + r) > qg) SA[t][r] = -INFINITY;
        }

        // ---- softmax (dual chains are independent) ----
        online_sm(SB, mB, lB, OB, quad);
        if (doA) online_sm(SA, mA, lA, OA, quad);

        // ---- P^T -> Ps (truncating bf16; P in [0, 256]) ----
        #pragma unroll
        for (int t = 0; t < 4; t++) {
            s16x4 p;
            #pragma unroll
            for (int r = 0; r < 4; r++)
                p[r] = (short)(__float_as_uint(SB[t][r]) >> 16);
            *(s16x4*)&Ps[wave][0][lm][(t * 16 + quad * 4) ^ swz] = p;
        }
        if (doA) {
            #pragma unroll
            for (int t = 0; t < 4; t++) {
                s16x4 p;
                #pragma unroll
                for (int r = 0; r < 4; r++)
                    p[r] = (short)(__float_as_uint(SA[t][r]) >> 16);
                *(s16x4*)&Ps[wave][1][lm][(t * 16 + quad * 4) ^ swz] = p;
            }
        }
        // wave-private slabs: no barrier (lgkmcnt ordering within wave)

        // ---- O += P V: shared Vt frag feeds both tiles ----
        s16x8 apB[2], apA[2];
        #pragma unroll
        for (int kc = 0; kc < 2; kc++)
            apB[kc] = *(const s16x8*)&Ps[wave][0][lm][(kc * 32 + quad * 8) ^ swz];
        __builtin_amdgcn_s_setprio(1);
        if (doA) {
            #pragma unroll
            for (int kc = 0; kc < 2; kc++)
                apA[kc] = *(const s16x8*)&Ps[wave][1][lm][(kc * 32 + quad * 8) ^ swz];
            #pragma unroll
            for (int t = 0; t < 4; t++)
                #pragma unroll
                for (int kc = 0; kc < 2; kc++) {
                    s16x8 bv = *(const s16x8*)&Vt[t * 16 + lm][(kc * 32 + quad * 8) ^ swz];
                    OB[t] = MFMA16(apB[kc], bv, OB[t]);
                    OA[t] = MFMA16(apA[kc], bv, OA[t]);
                }
        } else {
            #pragma unroll
            for (int t = 0; t < 4; t++)
                #pragma unroll
                for (int kc = 0; kc < 2; kc++) {
                    s16x8 bv = *(const s16x8*)&Vt[t * 16 + lm][(kc * 32 + quad * 8) ^ swz];
                    OB[t] = MFMA16(apB[kc], bv, OB[t]);
                }
        }
        __builtin_amdgcn_s_setprio(0);
    }

    // ---- epilogue: O row q = wave*16+quad*4+r, col d = t*16+lm ----
    float liA[4], liB[4];
    #pragma unroll
    for (int r = 0; r < 4; r++) {
        liA[r] = 1.0f / __shfl(lA, quad * 4 + r, 64);
        liB[r] = 1.0f / __shfl(lB, quad * 4 + r, 64);
    }
    #pragma unroll
    for (int t = 0; t < 4; t++)
        #pragma unroll
        for (int r = 0; r < 4; r++) {
            int d  = t * 16 + lm;
            int qa = q0A + wave * 16 + quad * 4 + r;
            int qb = q0B + wave * 16 + quad * 4 + r;
            Yb[((size_t)b * T_ + qa) * C_ + h * D_ + d] =
                (short)f2b(OA[t][r] * liA[r]);
            Yb[((size_t)b * T_ + qb) * C_ + h * D_ + d] =
                (short)f2b(OB[t][r] * liB[r]);
        }
}

// ---------------------------------------------------------------------------
extern "C" void kernel_launch(void* const* d_in, const int* in_sizes, int n_in,
                              void* d_out, int out_size, void* d_ws, size_t ws_size,
                              hipStream_t stream)
{
    const float* x      = (const float*)d_in[0];
    const float* W_attn = (const float*)d_in[1];
    const float* b_attn = (const float*)d_in[2];
    const float* W_proj = (const float*)d_in[3];
    const float* b_proj = (const float*)d_in[4];
    float* out = (float*)d_out;

    char* ws = (char*)d_ws;
    const size_t MB = 1024 * 1024;
    short* Qh   = (short*)(ws);            // 8 MB  [ 0, 8)
    short* Ql   = (short*)(ws +  8 * MB);  // 8 MB  [ 8,16)
    short* Kh   = (short*)(ws + 16 * MB);  // 8 MB  [16,24)
    short* Kl   = (short*)(ws + 24 * MB);  // 8 MB  [24,32)
    short* xh   = (short*)(ws + 32 * MB);  // 8 MB  [32,40)  dead after qkv_v
    short* xl   = (short*)(ws + 40 * MB);  // 8 MB  [40,48)  dead after qkv_qk
    short* WaTh = (short*)(ws + 48 * MB);  // 6 MB  [48,54)
    short* WaTl = (short*)(ws + 54 * MB);  // 6 MB  [54,60)
    short* WpT  = (short*)(ws + 60 * MB);  // 2 MB  [60,62)
    short* VT   = (short*)(ws + 40 * MB);  // 8 MB  aliases xl (born at qkv_v)
    short* Yb   = (short*)(ws + 32 * MB);  // 8 MB  aliases xh (born at attn)

    cvt_all<<<dim3(3072), 256, 0, stream>>>(x, xh, xl, W_attn, WaTh, WaTl,
                                            W_proj, WpT);

    qkv_qk <<<dim3(16, 32), 256, 0, stream>>>(xh, xl, WaTh, WaTl, b_attn,
                                              Qh, Ql, Kh, Kl);
    qkv_v  <<<dim3(8, 64), 256, 0, stream>>>(xh, WaTh + (size_t)2048 * C_,
                                             b_attn + 2048, VT);
    attn_mfma<<<dim3(512), 256, 0, stream>>>(Qh, Ql, Kh, Kl, VT, Yb);
    proj_mfma<<<dim3(8, 64), 256, 0, stream>>>(Yb, WpT, b_proj, out);
}

// Round 15
// 231.713 us; speedup vs baseline: 1.0650x; 1.0169x over previous
//
#include <hip/hip_runtime.h>
#include <hip/hip_bf16.h>

// Problem: CausalSelfAttention  B=2, T=2048, C=1024, H=16, D=64
// Round 27: epilogue write-coalescing for qkv_qk / qkv_v. R26 = best (235.6,
// attn setprio confirmed). Remaining counter-evidenced lever: WRITE_SIZE
// 58-81MB vs ~34MB ideal on qkv_qk (scattered 2B stores into [B,H,T,D]);
// qkv_v's VT scatter ~8x amplified. Fix: stage output tile through the
// dead staging LDS ([128][136] / [128][72] bf16, 16B-aligned padded rows),
// re-read as 16B vectors dense in the dest fast axis (d for Q/K, t for VT).
// Store instrs 64->16/thread; values bit-identical (same f2b path).
// attn (R17+setprio) / cvt_all / proj byte-identical to R26.
// ws (62 MB): Qh 8|Ql 8|Kh 8|Kl 8|xh 8(->Yb)|xl 8(->VT)|WaTh 6|WaTl 6|WpT 2

#define B_  2
#define T_  2048
#define C_  1024
#define H_  16
#define D_  64
#define M_  (B_ * T_)      // 4096
#define N3_ (3 * C_)       // 3072

typedef __attribute__((ext_vector_type(8))) short s16x8;
typedef __attribute__((ext_vector_type(4))) short s16x4;
typedef __attribute__((ext_vector_type(4))) float f32x4;

typedef const __attribute__((address_space(1))) unsigned int gu32_t;
typedef __attribute__((address_space(3))) unsigned int lu32_t;

#define MFMA16(a, b, c) __builtin_amdgcn_mfma_f32_16x16x32_bf16(a, b, c, 0, 0, 0)

__device__ __forceinline__ void gload_lds16(const short* g, short* l) {
    __builtin_amdgcn_global_load_lds((gu32_t*)g, (lu32_t*)l, 16, 0, 0);
}

__device__ __forceinline__ float b2f(unsigned short u) {
    return __uint_as_float(((unsigned)u) << 16);
}
__device__ __forceinline__ unsigned short f2b(float f) {   // RNE bf16 round
    unsigned u = __float_as_uint(f);
    return (unsigned short)((u + 0x7FFFu + ((u >> 16) & 1u)) >> 16);
}
__device__ __forceinline__ float fexp2(float x) {
#if __has_builtin(__builtin_amdgcn_exp2f)
    return __builtin_amdgcn_exp2f(x);
#else
    return exp2f(x);
#endif
}

// ---------------------------------------------------------------------------
// cvt_all: one dispatch for all input conversions (grid 3072).
// ---------------------------------------------------------------------------
__global__ __launch_bounds__(256) void cvt_all(
    const float* __restrict__ x,  short* __restrict__ xh,   short* __restrict__ xl,
    const float* __restrict__ Wa, short* __restrict__ WaTh, short* __restrict__ WaTl,
    const float* __restrict__ Wp, short* __restrict__ WpT)
{
    __shared__ short th[64][80];
    __shared__ short tl[64][80];
    const int tid = threadIdx.x;
    const int bid = blockIdx.x;

    if (bid < 2048) {
        int i = (bid * 256 + tid) * 8;
        float4 a = *(const float4*)&x[i];
        float4 b = *(const float4*)&x[i + 4];
        float v[8] = {a.x, a.y, a.z, a.w, b.x, b.y, b.z, b.w};
        s16x8 h, l;
        #pragma unroll
        for (int j = 0; j < 8; j++) {
            unsigned short hb = f2b(v[j]);
            h[j] = (short)hb;
            l[j] = (short)f2b(v[j] - b2f(hb));
        }
        *(s16x8*)&xh[i] = h;
        *(s16x8*)&xl[i] = l;
        return;
    }

    if (bid < 2816) {
        int r  = bid - 2048;            // 0..767
        int bx = r % 48, by = r / 48;   // (N3_/64, C_/64)
        const int k0 = by * 64, n0 = bx * 64;
        const int R = C_, Cn = N3_;
        {
            int rl = tid >> 4, cl = (tid & 15) * 4;
            #pragma unroll
            for (int i = 0; i < 4; i++) {
                int kr = rl + i * 16;
                float4 v4 = *(const float4*)&Wa[(size_t)(k0 + kr) * Cn + n0 + cl];
                float v[4] = {v4.x, v4.y, v4.z, v4.w};
                #pragma unroll
                for (int j = 0; j < 4; j++) {
                    unsigned short hb = f2b(v[j]);
                    th[cl + j][kr] = (short)hb;
                    tl[cl + j][kr] = (short)f2b(v[j] - b2f(hb));
                }
            }
        }
        __syncthreads();
        {
            int ro = tid >> 2, co = (tid & 3) * 16;
            *(s16x8*)&WaTh[(size_t)(n0 + ro) * R + k0 + co]     = *(s16x8*)&th[ro][co];
            *(s16x8*)&WaTh[(size_t)(n0 + ro) * R + k0 + co + 8] = *(s16x8*)&th[ro][co + 8];
            *(s16x8*)&WaTl[(size_t)(n0 + ro) * R + k0 + co]     = *(s16x8*)&tl[ro][co];
            *(s16x8*)&WaTl[(size_t)(n0 + ro) * R + k0 + co + 8] = *(s16x8*)&tl[ro][co + 8];
        }
        return;
    }

    {
        int r  = bid - 2816;            // 0..255
        int bx = r & 15, by = r >> 4;   // (C_/64, C_/64)
        const int k0 = by * 64, n0 = bx * 64;
        const int R = C_, Cn = C_;
        {
            int rl = tid >> 4, cl = (tid & 15) * 4;
            #pragma unroll
            for (int i = 0; i < 4; i++) {
                int kr = rl + i * 16;
                float4 v = *(const float4*)&Wp[(size_t)(k0 + kr) * Cn + n0 + cl];
                th[cl + 0][kr] = (short)f2b(v.x);
                th[cl + 1][kr] = (short)f2b(v.y);
                th[cl + 2][kr] = (short)f2b(v.z);
                th[cl + 3][kr] = (short)f2b(v.w);
            }
        }
        __syncthreads();
        {
            int ro = tid >> 2, co = (tid & 3) * 16;
            *(s16x8*)&WpT[(size_t)(n0 + ro) * R + k0 + co]     = *(s16x8*)&th[ro][co];
            *(s16x8*)&WpT[(size_t)(n0 + ro) * R + k0 + co + 8] = *(s16x8*)&th[ro][co + 8];
        }
    }
}

// ---------------------------------------------------------------------------
// qkv_qk: Q,K columns (N=2048), bf16x3, hi/lo. 128x128 tile, XCD remap,
// BK=64 panels, LDS 64 KB (merged SMEM), 0-conflict granule swizzle.
// NEW: epilogue stages tile through LDS [128][136] -> 16B coalesced stores.
// ---------------------------------------------------------------------------
__global__ __launch_bounds__(256) void qkv_qk(
    const short* __restrict__ Ah, const short* __restrict__ Al,
    const short* __restrict__ BTh, const short* __restrict__ BTl,
    const float* __restrict__ bias,
    short* __restrict__ Qh, short* __restrict__ Ql,
    short* __restrict__ Kh, short* __restrict__ Kl)
{
    __shared__ short SMEM[32768];   // 64 KB: Ash|Asl|Bsh|Bsl, 2-buf each
#define QK_ASH(p) (&SMEM[(p) * 4096])
#define QK_ASL(p) (&SMEM[8192 + (p) * 4096])
#define QK_BSH(p) (&SMEM[16384 + (p) * 4096])
#define QK_BSL(p) (&SMEM[24576 + (p) * 4096])

    const int tid  = threadIdx.x;
    const int wave = tid >> 6, lane = tid & 63;
    const int wm = wave >> 1, wn = wave & 1;
    const int lm = lane & 15, lq = lane >> 4;
    const int fid = blockIdx.y * 16 + blockIdx.x;
    const int wg  = (fid & 7) * 64 + (fid >> 3);
    const int n0  = (wg & 15) * 128;
    const int m0  = (wg >> 4) * 128;
    const int gr  = (lane >> 2);
    const int gc  = (((lane & 3) ^ ((lane >> 3) & 3)) << 3);
    const int sg  = ((lq ^ ((lm >> 1) & 3)) << 3);

    f32x4 acc[4][4] = {};

    for (int k0 = 0; k0 < C_; k0 += 64) {
        __syncthreads();
        #pragma unroll
        for (int p = 0; p < 2; p++) {
            int kp = k0 + p * 32;
            #pragma unroll
            for (int j = 0; j < 2; j++) {
                int s = wave * 2 + j;
                int row = s * 16 + gr;
                size_t ga = (size_t)(m0 + row) * C_ + kp + gc;
                size_t gb = (size_t)(n0 + row) * C_ + kp + gc;
                gload_lds16(&Ah[ga],  QK_ASH(p) + s * 512);
                gload_lds16(&Al[ga],  QK_ASL(p) + s * 512);
                gload_lds16(&BTh[gb], QK_BSH(p) + s * 512);
                gload_lds16(&BTl[gb], QK_BSL(p) + s * 512);
            }
        }
        __syncthreads();

        #pragma unroll
        for (int p = 0; p < 2; p++) {
            s16x8 ah[4], al[4], bh[4], bl[4];
            #pragma unroll
            for (int mi = 0; mi < 4; mi++) {
                int r = wm * 64 + mi * 16 + lm;
                ah[mi] = *(const s16x8*)&QK_ASH(p)[r * 32 + sg];
                al[mi] = *(const s16x8*)&QK_ASL(p)[r * 32 + sg];
            }
            #pragma unroll
            for (int nj = 0; nj < 4; nj++) {
                int r = wn * 64 + nj * 16 + lm;
                bh[nj] = *(const s16x8*)&QK_BSH(p)[r * 32 + sg];
                bl[nj] = *(const s16x8*)&QK_BSL(p)[r * 32 + sg];
            }
            #pragma unroll
            for (int mi = 0; mi < 4; mi++)
                #pragma unroll
                for (int nj = 0; nj < 4; nj++) {
                    acc[mi][nj] = MFMA16(ah[mi], bh[nj], acc[mi][nj]);
                    acc[mi][nj] = MFMA16(ah[mi], bl[nj], acc[mi][nj]);
                    acc[mi][nj] = MFMA16(al[mi], bh[nj], acc[mi][nj]);
                }
        }
    }

    // ---- epilogue: LDS transpose -> coalesced 16B stores (hi, then lo) ----
    // tr = SMEM as [128][136] bf16 (272B rows: 16B-aligned, bank-spread).
    short* tr = SMEM;
    #pragma unroll
    for (int pass = 0; pass < 2; pass++) {
        __syncthreads();                 // staging (or prev pass reads) done
        #pragma unroll
        for (int nj = 0; nj < 4; nj++) {
            int nl = wn * 64 + nj * 16 + lm;
            int n  = n0 + nl;
            float bv = bias[n];
            // Q carries sqrt(D)=8 and log2(e): softmax runs in exp2 domain
            float scale = (n >> 10) ? 1.0f : 11.541560327111708f;
            #pragma unroll
            for (int mi = 0; mi < 4; mi++) {
                #pragma unroll
                for (int r = 0; r < 4; r++) {
                    int ml = wm * 64 + mi * 16 + lq * 4 + r;
                    float v = (acc[mi][nj][r] + bv) * scale;
                    unsigned short hb = f2b(v);
                    unsigned short val = (pass == 0) ? hb
                                       : f2b(v - b2f(hb));
                    tr[ml * 136 + nl] = (short)val;
                }
            }
        }
        __syncthreads();
        #pragma unroll
        for (int i = 0; i < 8; i++) {
            int g  = i * 256 + tid;          // 0..2047
            int ml = g >> 4;                 // 0..127
            int nc = (g & 15) * 8;           // 0..120
            s16x8 vv = *(const s16x8*)&tr[ml * 136 + nc];
            int m = m0 + ml, n = n0 + nc;
            int isK = n >> 10;
            int c = n & (C_ - 1);
            int h = c >> 6, d = c & (D_ - 1);
            int bb = m >> 11, t = m & (T_ - 1);
            short* dst = (pass == 0) ? (isK ? Kh : Qh) : (isK ? Kl : Ql);
            *(s16x8*)&dst[(((size_t)bb * H_ + h) * T_ + t) * D_ + d] = vv;
        }
    }
#undef QK_ASH
#undef QK_ASL
#undef QK_BSH
#undef QK_BSL
}

// ---------------------------------------------------------------------------
// qkv_v: V columns (N=1024), single bf16 -> VT [B,H,D,T]. 64x128 tile, XCD
// remap, BK=64 panels, LDS 24 KB (merged). NEW: epilogue stages through LDS
// [128][72] -> 16B stores dense in t (was 8B at 4KB stride, ~8x amplified).
// ---------------------------------------------------------------------------
__global__ __launch_bounds__(256, 4) void qkv_v(
    const short* __restrict__ Ah, const short* __restrict__ BTh,
    const float* __restrict__ bias, short* __restrict__ VT)
{
    __shared__ short SMEM[12288];   // 24 KB: Ash(2x2048) | Bsh(2x4096)
#define V_ASH(p) (&SMEM[(p) * 2048])
#define V_BSH(p) (&SMEM[4096 + (p) * 4096])

    const int tid  = threadIdx.x;
    const int wave = tid >> 6, lane = tid & 63;
    const int wm = wave >> 1, wn = wave & 1;
    const int lm = lane & 15, lq = lane >> 4;
    const int fid = blockIdx.y * 8 + blockIdx.x;
    const int wg  = (fid & 7) * 64 + (fid >> 3);
    const int n0  = (wg & 7) * 128;
    const int m0  = (wg >> 3) * 64;
    const int gr  = (lane >> 2);
    const int gc  = (((lane & 3) ^ ((lane >> 3) & 3)) << 3);
    const int sg  = ((lq ^ ((lm >> 1) & 3)) << 3);

    f32x4 acc[2][4] = {};

    for (int k0 = 0; k0 < C_; k0 += 64) {
        __syncthreads();
        #pragma unroll
        for (int p = 0; p < 2; p++) {
            int kp = k0 + p * 32;
            int rowA = wave * 16 + gr;
            gload_lds16(&Ah[(size_t)(m0 + rowA) * C_ + kp + gc], V_ASH(p) + wave * 512);
            #pragma unroll
            for (int j = 0; j < 2; j++) {
                int s = wave * 2 + j;
                int rowB = s * 16 + gr;
                gload_lds16(&BTh[(size_t)(n0 + rowB) * C_ + kp + gc], V_BSH(p) + s * 512);
            }
        }
        __syncthreads();

        #pragma unroll
        for (int p = 0; p < 2; p++) {
            s16x8 af[2], bfr[4];
            #pragma unroll
            for (int mi = 0; mi < 2; mi++)
                af[mi] = *(const s16x8*)&V_ASH(p)[(wm * 32 + mi * 16 + lm) * 32 + sg];
            #pragma unroll
            for (int nj = 0; nj < 4; nj++)
                bfr[nj] = *(const s16x8*)&V_BSH(p)[(wn * 64 + nj * 16 + lm) * 32 + sg];
            #pragma unroll
            for (int mi = 0; mi < 2; mi++)
                #pragma unroll
                for (int nj = 0; nj < 4; nj++)
                    acc[mi][nj] = MFMA16(af[mi], bfr[nj], acc[mi][nj]);
        }
    }

    // ---- epilogue: LDS transpose [n][m] -> 16B stores dense in t ----
    short* tr = SMEM;                    // [128][72] = 9216 shorts
    __syncthreads();
    #pragma unroll
    for (int nj = 0; nj < 4; nj++) {
        int nl = wn * 64 + nj * 16 + lm;     // 0..127
        float bv = bias[n0 + nl];
        #pragma unroll
        for (int mi = 0; mi < 2; mi++) {
            #pragma unroll
            for (int r = 0; r < 4; r++) {
                int ml = wm * 32 + mi * 16 + lq * 4 + r;   // 0..63
                tr[nl * 72 + ml] = (short)f2b(acc[mi][nj][r] + bv);
            }
        }
    }
    __syncthreads();
    #pragma unroll
    for (int i = 0; i < 4; i++) {
        int g  = i * 256 + tid;          // 0..1023
        int nl = g >> 3;                 // 0..127
        int mc = (g & 7) * 8;            // 0..56
        s16x8 vv = *(const s16x8*)&tr[nl * 72 + mc];
        int n = n0 + nl, m = m0 + mc;
        int h = n >> 6, d = n & (D_ - 1);
        int bb = m >> 11, t = m & (T_ - 1);
        *(s16x8*)&VT[(((size_t)bb * H_ + h) * D_ + d) * T_ + t] = vv;
    }
#undef V_ASH
#undef V_BSH
}

// ---------------------------------------------------------------------------
// proj: out fp32 [M,C] = Yb(bf16) @ WpT(bf16) + bias. 64x128 tile, XCD
// remap, BK=64 panels, LDS 24 KB. (R24; fp32 row-major out already coalesced)
// ---------------------------------------------------------------------------
__global__ __launch_bounds__(256, 4) void proj_mfma(
    const short* __restrict__ Ah, const short* __restrict__ BTh,
    const float* __restrict__ bias, float* __restrict__ out)
{
    __shared__ short Ash[2][64 * 32];
    __shared__ short Bsh[2][128 * 32];

    const int tid  = threadIdx.x;
    const int wave = tid >> 6, lane = tid & 63;
    const int wm = wave >> 1, wn = wave & 1;
    const int lm = lane & 15, lq = lane >> 4;
    const int fid = blockIdx.y * 8 + blockIdx.x;
    const int wg  = (fid & 7) * 64 + (fid >> 3);
    const int n0  = (wg & 7) * 128;
    const int m0  = (wg >> 3) * 64;
    const int gr  = (lane >> 2);
    const int gc  = (((lane & 3) ^ ((lane >> 3) & 3)) << 3);
    const int sg  = ((lq ^ ((lm >> 1) & 3)) << 3);

    f32x4 acc[2][4] = {};

    for (int k0 = 0; k0 < C_; k0 += 64) {
        __syncthreads();
        #pragma unroll
        for (int p = 0; p < 2; p++) {
            int kp = k0 + p * 32;
            int rowA = wave * 16 + gr;
            gload_lds16(&Ah[(size_t)(m0 + rowA) * C_ + kp + gc], &Ash[p][wave * 512]);
            #pragma unroll
            for (int j = 0; j < 2; j++) {
                int s = wave * 2 + j;
                int rowB = s * 16 + gr;
                gload_lds16(&BTh[(size_t)(n0 + rowB) * C_ + kp + gc], &Bsh[p][s * 512]);
            }
        }
        __syncthreads();

        #pragma unroll
        for (int p = 0; p < 2; p++) {
            s16x8 af[2], bfr[4];
            #pragma unroll
            for (int mi = 0; mi < 2; mi++)
                af[mi] = *(const s16x8*)&Ash[p][(wm * 32 + mi * 16 + lm) * 32 + sg];
            #pragma unroll
            for (int nj = 0; nj < 4; nj++)
                bfr[nj] = *(const s16x8*)&Bsh[p][(wn * 64 + nj * 16 + lm) * 32 + sg];
            #pragma unroll
            for (int mi = 0; mi < 2; mi++)
                #pragma unroll
                for (int nj = 0; nj < 4; nj++)
                    acc[mi][nj] = MFMA16(af[mi], bfr[nj], acc[mi][nj]);
        }
    }

    #pragma unroll
    for (int nj = 0; nj < 4; nj++) {
        int n = n0 + wn * 64 + nj * 16 + lm;
        float bv = bias[n];
        #pragma unroll
        for (int mi = 0; mi < 2; mi++) {
            #pragma unroll
            for (int r = 0; r < 4; r++) {
                int m = m0 + wm * 32 + mi * 16 + lq * 4 + r;
                out[(size_t)m * C_ + n] = acc[mi][nj][r] + bv;
            }
        }
    }
}

// ---------------------------------------------------------------------------
// online softmax (exp2 domain) with defer-max (THR=8). S in/out: S^T frag,
// per-thread 16 values for q-row lm. On exit S holds P = exp2(S - m).
// ---------------------------------------------------------------------------
__device__ __forceinline__ void online_sm(
    f32x4 S[4], float& mrow, float& lrow, f32x4 O[4], int quad)
{
    float v[16];
    #pragma unroll
    for (int t = 0; t < 4; t++)
        #pragma unroll
        for (int r = 0; r < 4; r++) v[t * 4 + r] = S[t][r];
    #pragma unroll
    for (int s = 8; s; s >>= 1)
        #pragma unroll
        for (int i = 0; i < s; i++) v[i] = fmaxf(v[i], v[i + s]);
    float rm = v[0];
    rm = fmaxf(rm, __shfl_xor(rm, 16, 64));
    rm = fmaxf(rm, __shfl_xor(rm, 32, 64));
    // defer-max: only rescale when some row grew by > 8 (=2^8 headroom)
    if (!__all(rm - mrow <= 8.f)) {
        float mnew  = fmaxf(mrow, rm);
        float alpha = fexp2(mrow - mnew);
        mrow = mnew;
        lrow *= alpha;
        float al[4];
        #pragma unroll
        for (int r = 0; r < 4; r++) al[r] = __shfl(alpha, quad * 4 + r, 64);
        #pragma unroll
        for (int t = 0; t < 4; t++)
            #pragma unroll
            for (int r = 0; r < 4; r++) O[t][r] *= al[r];
    }
    float sv[16];
    #pragma unroll
    for (int t = 0; t < 4; t++)
        #pragma unroll
        for (int r = 0; r < 4; r++) {
            float p = fexp2(S[t][r] - mrow);
            S[t][r] = p;
            sv[t * 4 + r] = p;
        }
    #pragma unroll
    for (int s = 8; s; s >>= 1)
        #pragma unroll
        for (int i = 0; i < s; i++) sv[i] += sv[i + s];
    float rs = sv[0];
    rs += __shfl_xor(rs, 16, 64);
    rs += __shfl_xor(rs, 32, 64);
    lrow += rs;
}

// ---------------------------------------------------------------------------
// MFMA flash attention, S^T layout, PAIRED q-tiles per block. Grid 512.
// R17-exact structure + T5 setprio around the two MFMA clusters (R26 win).
// LDS 40KB XOR-swizzled, 2 blocks/CU, exp2-domain defer-max softmax.
// ---------------------------------------------------------------------------
__global__ __launch_bounds__(256, 2) void attn_mfma(
    const short* __restrict__ Qh, const short* __restrict__ Ql,
    const short* __restrict__ Kh, const short* __restrict__ Kl,
    const short* __restrict__ VT, short* __restrict__ Yb)
{
    __shared__ short Ksh[64][64], Ksl[64][64];   // [key][d], XOR-swizzled
    __shared__ short Vt [64][64];                // [d][key], XOR-swizzled
    __shared__ short Ps [4][2][16][64];          // per-wave P slabs (B=0,A=1)

    const int tid  = threadIdx.x;
    const int wave = tid >> 6, lane = tid & 63;
    const int lm   = lane & 15, quad = lane >> 4;
    const int swz  = (lm & 7) << 3;              // read-side XOR (shorts)

    const int bid = blockIdx.x;                  // 512 blocks
    const int xcd = bid & 7;
    const int r_  = bid >> 3;                    // 0..63 per XCD
    const int bhl = r_ & 3;
    const int u   = r_ >> 2;                     // 0..15
    const int g_  = u >> 3, j_ = u & 7;
    const int j   = g_ ? (15 - j_) : j_;         // CU slot pairs j with 15-j
    const int bh  = xcd * 4 + bhl;
    const int b   = bh >> 4, h = bh & (H_ - 1);
    const int qtA = j, qtB = 31 - j;
    const int q0A = qtA * 64, q0B = qtB * 64;
    const size_t base  = (size_t)bh * T_ * D_;   // Q,K: [b,h,t,d]
    const size_t vbase = (size_t)bh * D_ * T_;   // VT:  [b,h,d,t]

    const int src = tid >> 3;                    // staging row 0..31 (+32)
    const int sch = (tid & 7) * 8;               // linear global col (shorts)
    const int wsw = sch ^ ((src & 7) << 3);      // swizzled LDS write col

    // ---- Q frags direct from global (L2-hit, once per block) ----
    s16x8 bqhA[2], bqlA[2], bqhB[2], bqlB[2];
    #pragma unroll
    for (int kc = 0; kc < 2; kc++) {
        size_t ga = base + (size_t)(q0A + wave * 16 + lm) * D_ + kc * 32 + quad * 8;
        size_t gb = base + (size_t)(q0B + wave * 16 + lm) * D_ + kc * 32 + quad * 8;
        bqhA[kc] = *(const s16x8*)&Qh[ga];
        bqlA[kc] = *(const s16x8*)&Ql[ga];
        bqhB[kc] = *(const s16x8*)&Qh[gb];
        bqlB[kc] = *(const s16x8*)&Ql[gb];
    }

    // ---- prefetch k-tile 0 into registers ----
    s16x8 pkh[2], pkl[2], pvt[2];
    #pragma unroll
    for (int i = 0; i < 2; i++) {
        int row = i * 32 + src;
        size_t gk = base + (size_t)row * D_ + sch;
        pkh[i] = *(const s16x8*)&Kh[gk];
        pkl[i] = *(const s16x8*)&Kl[gk];
        pvt[i] = *(const s16x8*)&VT[vbase + (size_t)row * T_ + sch];
    }

    float mA = -INFINITY, lA = 0.f;
    float mB = -INFINITY, lB = 0.f;
    f32x4 OA[4] = {}, OB[4] = {};

    for (int kt = 0; kt <= qtB; kt++) {
        __syncthreads();                          // prev tile's readers done
        #pragma unroll
        for (int i = 0; i < 2; i++) {             // VGPR -> LDS (swizzled)
            int row = i * 32 + src;
            *(s16x8*)&Ksh[row][wsw] = pkh[i];
            *(s16x8*)&Ksl[row][wsw] = pkl[i];
            *(s16x8*)&Vt [row][wsw] = pvt[i];
        }
        if (kt < qtB) {                           // issue next tile's loads
            #pragma unroll
            for (int i = 0; i < 2; i++) {
                int row = i * 32 + src;
                size_t gk = base + (size_t)((kt + 1) * 64 + row) * D_ + sch;
                pkh[i] = *(const s16x8*)&Kh[gk];
                pkl[i] = *(const s16x8*)&Kl[gk];
                pvt[i] = *(const s16x8*)&VT[vbase + (size_t)row * T_ + (kt + 1) * 64 + sch];
            }
        }
        __syncthreads();

        const bool doA = (kt <= qtA);
        const int  qg  = wave * 16 + lm;

        f32x4 SB[4] = {}, SA[4] = {};
        __builtin_amdgcn_s_setprio(1);
        if (doA) {
            // dual: one k-frag read feeds 6 MFMAs (two independent chains)
            #pragma unroll
            for (int t = 0; t < 4; t++)
                #pragma unroll
                for (int kc = 0; kc < 2; kc++) {
                    s16x8 kh8 = *(const s16x8*)&Ksh[t * 16 + lm][(kc * 32 + quad * 8) ^ swz];
                    s16x8 kl8 = *(const s16x8*)&Ksl[t * 16 + lm][(kc * 32 + quad * 8) ^ swz];
                    SB[t] = MFMA16(kh8, bqhB[kc], SB[t]);
                    SB[t] = MFMA16(kl8, bqhB[kc], SB[t]);
                    SB[t] = MFMA16(kh8, bqlB[kc], SB[t]);
                    SA[t] = MFMA16(kh8, bqhA[kc], SA[t]);
                    SA[t] = MFMA16(kl8, bqhA[kc], SA[t]);
                    SA[t] = MFMA16(kh8, bqlA[kc], SA[t]);
                }
        } else {
            #pragma unroll
            for (int t = 0; t < 4; t++)
                #pragma unroll
                for (int kc = 0; kc < 2; kc++) {
                    s16x8 kh8 = *(const s16x8*)&Ksh[t * 16 + lm][(kc * 32 + quad * 8) ^ swz];
                    s16x8 kl8 = *(const s16x8*)&Ksl[t * 16 + lm][(kc * 32 + quad * 8) ^ swz];
                    SB[t] = MFMA16(kh8, bqhB[kc], SB[t]);
                    SB[t] = MFMA16(kl8, bqhB[kc], SB[t]);
                    SB[t] = MFMA16(kh8, bqlB[kc], SB[t]);
                }
        }
        __builtin_amdgcn_s_setprio(0);

        // causal masks (scale pre-folded into Q)
        if (kt == qtB) {
            #pragma unroll
            for (int t = 0; t < 4; t++)
                #pragma unroll
                for (int r = 0; r < 4; r++)
                    if ((t * 16 + quad * 4 + r) > qg) SB[t][r] = -INFINITY;
        }
        if (kt == qtA) {
            #pragma unroll
            for (int t = 0; t < 4; t++)
                #pragma unroll
                for (int r = 0; r < 4; r++)
                    if ((t * 16 + quad * 4 + r) > qg) SA[t][r] = -INFINITY;
        }

        // ---- softmax (dual chains are independent) ----
        online_sm(SB, mB, lB, OB, quad);
        if (doA) online_sm(SA, mA, lA, OA, quad);

        // ---- P^T -> Ps (truncating bf16; P in [0, 256]) ----
        #pragma unroll
        for (int t = 0; t < 4; t++) {
            s16x4 p;
            #pragma unroll
            for (int r = 0; r < 4; r++)
                p[r] = (short)(__float_as_uint(SB[t][r]) >> 16);
            *(s16x4*)&Ps[wave][0][lm][(t * 16 + quad * 4) ^ swz] = p;
        }
        if (doA) {
            #pragma unroll
            for (int t = 0; t < 4; t++) {
                s16x4 p;
                #pragma unroll
                for (int r = 0; r < 4; r++)
                    p[r] = (short)(__float_as_uint(SA[t][r]) >> 16);
                *(s16x4*)&Ps[wave][1][lm][(t * 16 + quad * 4) ^ swz] = p;
            }
        }
        // wave-private slabs: no barrier (lgkmcnt ordering within wave)

        // ---- O += P V: shared Vt frag feeds both tiles ----
        s16x8 apB[2], apA[2];
        #pragma unroll
        for (int kc = 0; kc < 2; kc++)
            apB[kc] = *(const s16x8*)&Ps[wave][0][lm][(kc * 32 + quad * 8) ^ swz];
        __builtin_amdgcn_s_setprio(1);
        if (doA) {
            #pragma unroll
            for (int kc = 0; kc < 2; kc++)
                apA[kc] = *(const s16x8*)&Ps[wave][1][lm][(kc * 32 + quad * 8) ^ swz];
            #pragma unroll
            for (int t = 0; t < 4; t++)
                #pragma unroll
                for (int kc = 0; kc < 2; kc++) {
                    s16x8 bv = *(const s16x8*)&Vt[t * 16 + lm][(kc * 32 + quad * 8) ^ swz];
                    OB[t] = MFMA16(apB[kc], bv, OB[t]);
                    OA[t] = MFMA16(apA[kc], bv, OA[t]);
                }
        } else {
            #pragma unroll
            for (int t = 0; t < 4; t++)
                #pragma unroll
                for (int kc = 0; kc < 2; kc++) {
                    s16x8 bv = *(const s16x8*)&Vt[t * 16 + lm][(kc * 32 + quad * 8) ^ swz];
                    OB[t] = MFMA16(apB[kc], bv, OB[t]);
                }
        }
        __builtin_amdgcn_s_setprio(0);
    }

    // ---- epilogue: O row q = wave*16+quad*4+r, col d = t*16+lm ----
    float liA[4], liB[4];
    #pragma unroll
    for (int r = 0; r < 4; r++) {
        liA[r] = 1.0f / __shfl(lA, quad * 4 + r, 64);
        liB[r] = 1.0f / __shfl(lB, quad * 4 + r, 64);
    }
    #pragma unroll
    for (int t = 0; t < 4; t++)
        #pragma unroll
        for (int r = 0; r < 4; r++) {
            int d  = t * 16 + lm;
            int qa = q0A + wave * 16 + quad * 4 + r;
            int qb = q0B + wave * 16 + quad * 4 + r;
            Yb[((size_t)b * T_ + qa) * C_ + h * D_ + d] =
                (short)f2b(OA[t][r] * liA[r]);
            Yb[((size_t)b * T_ + qb) * C_ + h * D_ + d] =
                (short)f2b(OB[t][r] * liB[r]);
        }
}

// ---------------------------------------------------------------------------
extern "C" void kernel_launch(void* const* d_in, const int* in_sizes, int n_in,
                              void* d_out, int out_size, void* d_ws, size_t ws_size,
                              hipStream_t stream)
{
    const float* x      = (const float*)d_in[0];
    const float* W_attn = (const float*)d_in[1];
    const float* b_attn = (const float*)d_in[2];
    const float* W_proj = (const float*)d_in[3];
    const float* b_proj = (const float*)d_in[4];
    float* out = (float*)d_out;

    char* ws = (char*)d_ws;
    const size_t MB = 1024 * 1024;
    short* Qh   = (short*)(ws);            // 8 MB  [ 0, 8)
    short* Ql   = (short*)(ws +  8 * MB);  // 8 MB  [ 8,16)
    short* Kh   = (short*)(ws + 16 * MB);  // 8 MB  [16,24)
    short* Kl   = (short*)(ws + 24 * MB);  // 8 MB  [24,32)
    short* xh   = (short*)(ws + 32 * MB);  // 8 MB  [32,40)  dead after qkv_v
    short* xl   = (short*)(ws + 40 * MB);  // 8 MB  [40,48)  dead after qkv_qk
    short* WaTh = (short*)(ws + 48 * MB);  // 6 MB  [48,54)
    short* WaTl = (short*)(ws + 54 * MB);  // 6 MB  [54,60)
    short* WpT  = (short*)(ws + 60 * MB);  // 2 MB  [60,62)
    short* VT   = (short*)(ws + 40 * MB);  // 8 MB  aliases xl (born at qkv_v)
    short* Yb   = (short*)(ws + 32 * MB);  // 8 MB  aliases xh (born at attn)

    cvt_all<<<dim3(3072), 256, 0, stream>>>(x, xh, xl, W_attn, WaTh, WaTl,
                                            W_proj, WpT);

    qkv_qk <<<dim3(16, 32), 256, 0, stream>>>(xh, xl, WaTh, WaTl, b_attn,
                                              Qh, Ql, Kh, Kl);
    qkv_v  <<<dim3(8, 64), 256, 0, stream>>>(xh, WaTh + (size_t)2048 * C_,
                                             b_attn + 2048, VT);
    attn_mfma<<<dim3(512), 256, 0, stream>>>(Qh, Ql, Kh, Kl, VT, Yb);
    proj_mfma<<<dim3(8, 64), 256, 0, stream>>>(Yb, WpT, b_proj, out);
}

// Round 16
// 229.937 us; speedup vs baseline: 1.0732x; 1.0077x over previous
//
#include <hip/hip_runtime.h>
#include <hip/hip_bf16.h>

// Problem: CausalSelfAttention  B=2, T=2048, C=1024, H=16, D=64
// Round 28: attn single-barrier K/V double-buffer (T3 minimum 2-phase).
// R27 = best (231.7; write-coalescing confirmed, attn sole top kernel ~61us).
// Found flaw: attn's barrier-2 (__syncthreads vmcnt(0)) drains the K/V
// prefetch issued right before it -> load latency serial EVERY iteration,
// plus 2 barriers + serial LDS-write burst. Fix: dbuf K/V (LDS 40->64KB,
// still 2 blocks/CU): per iter {write tile kt+1 -> buf[cur^1] + issue loads
// kt+2} overlap compute(buf[cur]); ONE __syncthreads at end. Loads get a
// full compute phase to land. Barriers 66->34. WAR/RAW safe: reads of
// buf[cur^1] finished before previous barrier; writes visible after it.
// All else byte-identical to R27 (swizzle/defer-max/setprio/epilogues).
// ws (62 MB): Qh 8|Ql 8|Kh 8|Kl 8|xh 8(->Yb)|xl 8(->VT)|WaTh 6|WaTl 6|WpT 2

#define B_  2
#define T_  2048
#define C_  1024
#define H_  16
#define D_  64
#define M_  (B_ * T_)      // 4096
#define N3_ (3 * C_)       // 3072

typedef __attribute__((ext_vector_type(8))) short s16x8;
typedef __attribute__((ext_vector_type(4))) short s16x4;
typedef __attribute__((ext_vector_type(4))) float f32x4;

typedef const __attribute__((address_space(1))) unsigned int gu32_t;
typedef __attribute__((address_space(3))) unsigned int lu32_t;

#define MFMA16(a, b, c) __builtin_amdgcn_mfma_f32_16x16x32_bf16(a, b, c, 0, 0, 0)

__device__ __forceinline__ void gload_lds16(const short* g, short* l) {
    __builtin_amdgcn_global_load_lds((gu32_t*)g, (lu32_t*)l, 16, 0, 0);
}

__device__ __forceinline__ float b2f(unsigned short u) {
    return __uint_as_float(((unsigned)u) << 16);
}
__device__ __forceinline__ unsigned short f2b(float f) {   // RNE bf16 round
    unsigned u = __float_as_uint(f);
    return (unsigned short)((u + 0x7FFFu + ((u >> 16) & 1u)) >> 16);
}
__device__ __forceinline__ float fexp2(float x) {
#if __has_builtin(__builtin_amdgcn_exp2f)
    return __builtin_amdgcn_exp2f(x);
#else
    return exp2f(x);
#endif
}

// ---------------------------------------------------------------------------
// cvt_all: one dispatch for all input conversions (grid 3072).
// ---------------------------------------------------------------------------
__global__ __launch_bounds__(256) void cvt_all(
    const float* __restrict__ x,  short* __restrict__ xh,   short* __restrict__ xl,
    const float* __restrict__ Wa, short* __restrict__ WaTh, short* __restrict__ WaTl,
    const float* __restrict__ Wp, short* __restrict__ WpT)
{
    __shared__ short th[64][80];
    __shared__ short tl[64][80];
    const int tid = threadIdx.x;
    const int bid = blockIdx.x;

    if (bid < 2048) {
        int i = (bid * 256 + tid) * 8;
        float4 a = *(const float4*)&x[i];
        float4 b = *(const float4*)&x[i + 4];
        float v[8] = {a.x, a.y, a.z, a.w, b.x, b.y, b.z, b.w};
        s16x8 h, l;
        #pragma unroll
        for (int j = 0; j < 8; j++) {
            unsigned short hb = f2b(v[j]);
            h[j] = (short)hb;
            l[j] = (short)f2b(v[j] - b2f(hb));
        }
        *(s16x8*)&xh[i] = h;
        *(s16x8*)&xl[i] = l;
        return;
    }

    if (bid < 2816) {
        int r  = bid - 2048;            // 0..767
        int bx = r % 48, by = r / 48;   // (N3_/64, C_/64)
        const int k0 = by * 64, n0 = bx * 64;
        const int R = C_, Cn = N3_;
        {
            int rl = tid >> 4, cl = (tid & 15) * 4;
            #pragma unroll
            for (int i = 0; i < 4; i++) {
                int kr = rl + i * 16;
                float4 v4 = *(const float4*)&Wa[(size_t)(k0 + kr) * Cn + n0 + cl];
                float v[4] = {v4.x, v4.y, v4.z, v4.w};
                #pragma unroll
                for (int j = 0; j < 4; j++) {
                    unsigned short hb = f2b(v[j]);
                    th[cl + j][kr] = (short)hb;
                    tl[cl + j][kr] = (short)f2b(v[j] - b2f(hb));
                }
            }
        }
        __syncthreads();
        {
            int ro = tid >> 2, co = (tid & 3) * 16;
            *(s16x8*)&WaTh[(size_t)(n0 + ro) * R + k0 + co]     = *(s16x8*)&th[ro][co];
            *(s16x8*)&WaTh[(size_t)(n0 + ro) * R + k0 + co + 8] = *(s16x8*)&th[ro][co + 8];
            *(s16x8*)&WaTl[(size_t)(n0 + ro) * R + k0 + co]     = *(s16x8*)&tl[ro][co];
            *(s16x8*)&WaTl[(size_t)(n0 + ro) * R + k0 + co + 8] = *(s16x8*)&tl[ro][co + 8];
        }
        return;
    }

    {
        int r  = bid - 2816;            // 0..255
        int bx = r & 15, by = r >> 4;   // (C_/64, C_/64)
        const int k0 = by * 64, n0 = bx * 64;
        const int R = C_, Cn = C_;
        {
            int rl = tid >> 4, cl = (tid & 15) * 4;
            #pragma unroll
            for (int i = 0; i < 4; i++) {
                int kr = rl + i * 16;
                float4 v = *(const float4*)&Wp[(size_t)(k0 + kr) * Cn + n0 + cl];
                th[cl + 0][kr] = (short)f2b(v.x);
                th[cl + 1][kr] = (short)f2b(v.y);
                th[cl + 2][kr] = (short)f2b(v.z);
                th[cl + 3][kr] = (short)f2b(v.w);
            }
        }
        __syncthreads();
        {
            int ro = tid >> 2, co = (tid & 3) * 16;
            *(s16x8*)&WpT[(size_t)(n0 + ro) * R + k0 + co]     = *(s16x8*)&th[ro][co];
            *(s16x8*)&WpT[(size_t)(n0 + ro) * R + k0 + co + 8] = *(s16x8*)&th[ro][co + 8];
        }
    }
}

// ---------------------------------------------------------------------------
// qkv_qk: Q,K columns (N=2048), bf16x3, hi/lo. 128x128 tile, XCD remap,
// BK=64 panels, LDS 64 KB (merged SMEM), 0-conflict granule swizzle.
// Epilogue stages tile through LDS [128][136] -> 16B coalesced stores. (R27)
// ---------------------------------------------------------------------------
__global__ __launch_bounds__(256) void qkv_qk(
    const short* __restrict__ Ah, const short* __restrict__ Al,
    const short* __restrict__ BTh, const short* __restrict__ BTl,
    const float* __restrict__ bias,
    short* __restrict__ Qh, short* __restrict__ Ql,
    short* __restrict__ Kh, short* __restrict__ Kl)
{
    __shared__ short SMEM[32768];   // 64 KB: Ash|Asl|Bsh|Bsl, 2-buf each
#define QK_ASH(p) (&SMEM[(p) * 4096])
#define QK_ASL(p) (&SMEM[8192 + (p) * 4096])
#define QK_BSH(p) (&SMEM[16384 + (p) * 4096])
#define QK_BSL(p) (&SMEM[24576 + (p) * 4096])

    const int tid  = threadIdx.x;
    const int wave = tid >> 6, lane = tid & 63;
    const int wm = wave >> 1, wn = wave & 1;
    const int lm = lane & 15, lq = lane >> 4;
    const int fid = blockIdx.y * 16 + blockIdx.x;
    const int wg  = (fid & 7) * 64 + (fid >> 3);
    const int n0  = (wg & 15) * 128;
    const int m0  = (wg >> 4) * 128;
    const int gr  = (lane >> 2);
    const int gc  = (((lane & 3) ^ ((lane >> 3) & 3)) << 3);
    const int sg  = ((lq ^ ((lm >> 1) & 3)) << 3);

    f32x4 acc[4][4] = {};

    for (int k0 = 0; k0 < C_; k0 += 64) {
        __syncthreads();
        #pragma unroll
        for (int p = 0; p < 2; p++) {
            int kp = k0 + p * 32;
            #pragma unroll
            for (int j = 0; j < 2; j++) {
                int s = wave * 2 + j;
                int row = s * 16 + gr;
                size_t ga = (size_t)(m0 + row) * C_ + kp + gc;
                size_t gb = (size_t)(n0 + row) * C_ + kp + gc;
                gload_lds16(&Ah[ga],  QK_ASH(p) + s * 512);
                gload_lds16(&Al[ga],  QK_ASL(p) + s * 512);
                gload_lds16(&BTh[gb], QK_BSH(p) + s * 512);
                gload_lds16(&BTl[gb], QK_BSL(p) + s * 512);
            }
        }
        __syncthreads();

        #pragma unroll
        for (int p = 0; p < 2; p++) {
            s16x8 ah[4], al[4], bh[4], bl[4];
            #pragma unroll
            for (int mi = 0; mi < 4; mi++) {
                int r = wm * 64 + mi * 16 + lm;
                ah[mi] = *(const s16x8*)&QK_ASH(p)[r * 32 + sg];
                al[mi] = *(const s16x8*)&QK_ASL(p)[r * 32 + sg];
            }
            #pragma unroll
            for (int nj = 0; nj < 4; nj++) {
                int r = wn * 64 + nj * 16 + lm;
                bh[nj] = *(const s16x8*)&QK_BSH(p)[r * 32 + sg];
                bl[nj] = *(const s16x8*)&QK_BSL(p)[r * 32 + sg];
            }
            #pragma unroll
            for (int mi = 0; mi < 4; mi++)
                #pragma unroll
                for (int nj = 0; nj < 4; nj++) {
                    acc[mi][nj] = MFMA16(ah[mi], bh[nj], acc[mi][nj]);
                    acc[mi][nj] = MFMA16(ah[mi], bl[nj], acc[mi][nj]);
                    acc[mi][nj] = MFMA16(al[mi], bh[nj], acc[mi][nj]);
                }
        }
    }

    // ---- epilogue: LDS transpose -> coalesced 16B stores (hi, then lo) ----
    short* tr = SMEM;   // [128][136] bf16
    #pragma unroll
    for (int pass = 0; pass < 2; pass++) {
        __syncthreads();                 // staging (or prev pass reads) done
        #pragma unroll
        for (int nj = 0; nj < 4; nj++) {
            int nl = wn * 64 + nj * 16 + lm;
            int n  = n0 + nl;
            float bv = bias[n];
            // Q carries sqrt(D)=8 and log2(e): softmax runs in exp2 domain
            float scale = (n >> 10) ? 1.0f : 11.541560327111708f;
            #pragma unroll
            for (int mi = 0; mi < 4; mi++) {
                #pragma unroll
                for (int r = 0; r < 4; r++) {
                    int ml = wm * 64 + mi * 16 + lq * 4 + r;
                    float v = (acc[mi][nj][r] + bv) * scale;
                    unsigned short hb = f2b(v);
                    unsigned short val = (pass == 0) ? hb
                                       : f2b(v - b2f(hb));
                    tr[ml * 136 + nl] = (short)val;
                }
            }
        }
        __syncthreads();
        #pragma unroll
        for (int i = 0; i < 8; i++) {
            int g  = i * 256 + tid;          // 0..2047
            int ml = g >> 4;                 // 0..127
            int nc = (g & 15) * 8;           // 0..120
            s16x8 vv = *(const s16x8*)&tr[ml * 136 + nc];
            int m = m0 + ml, n = n0 + nc;
            int isK = n >> 10;
            int c = n & (C_ - 1);
            int h = c >> 6, d = c & (D_ - 1);
            int bb = m >> 11, t = m & (T_ - 1);
            short* dst = (pass == 0) ? (isK ? Kh : Qh) : (isK ? Kl : Ql);
            *(s16x8*)&dst[(((size_t)bb * H_ + h) * T_ + t) * D_ + d] = vv;
        }
    }
#undef QK_ASH
#undef QK_ASL
#undef QK_BSH
#undef QK_BSL
}

// ---------------------------------------------------------------------------
// qkv_v: V columns (N=1024), single bf16 -> VT [B,H,D,T]. 64x128 tile, XCD
// remap, BK=64 panels, LDS 24 KB (merged). Epilogue stages through LDS
// [128][72] -> 16B stores dense in t. (R27)
// ---------------------------------------------------------------------------
__global__ __launch_bounds__(256, 4) void qkv_v(
    const short* __restrict__ Ah, const short* __restrict__ BTh,
    const float* __restrict__ bias, short* __restrict__ VT)
{
    __shared__ short SMEM[12288];   // 24 KB: Ash(2x2048) | Bsh(2x4096)
#define V_ASH(p) (&SMEM[(p) * 2048])
#define V_BSH(p) (&SMEM[4096 + (p) * 4096])

    const int tid  = threadIdx.x;
    const int wave = tid >> 6, lane = tid & 63;
    const int wm = wave >> 1, wn = wave & 1;
    const int lm = lane & 15, lq = lane >> 4;
    const int fid = blockIdx.y * 8 + blockIdx.x;
    const int wg  = (fid & 7) * 64 + (fid >> 3);
    const int n0  = (wg & 7) * 128;
    const int m0  = (wg >> 3) * 64;
    const int gr  = (lane >> 2);
    const int gc  = (((lane & 3) ^ ((lane >> 3) & 3)) << 3);
    const int sg  = ((lq ^ ((lm >> 1) & 3)) << 3);

    f32x4 acc[2][4] = {};

    for (int k0 = 0; k0 < C_; k0 += 64) {
        __syncthreads();
        #pragma unroll
        for (int p = 0; p < 2; p++) {
            int kp = k0 + p * 32;
            int rowA = wave * 16 + gr;
            gload_lds16(&Ah[(size_t)(m0 + rowA) * C_ + kp + gc], V_ASH(p) + wave * 512);
            #pragma unroll
            for (int j = 0; j < 2; j++) {
                int s = wave * 2 + j;
                int rowB = s * 16 + gr;
                gload_lds16(&BTh[(size_t)(n0 + rowB) * C_ + kp + gc], V_BSH(p) + s * 512);
            }
        }
        __syncthreads();

        #pragma unroll
        for (int p = 0; p < 2; p++) {
            s16x8 af[2], bfr[4];
            #pragma unroll
            for (int mi = 0; mi < 2; mi++)
                af[mi] = *(const s16x8*)&V_ASH(p)[(wm * 32 + mi * 16 + lm) * 32 + sg];
            #pragma unroll
            for (int nj = 0; nj < 4; nj++)
                bfr[nj] = *(const s16x8*)&V_BSH(p)[(wn * 64 + nj * 16 + lm) * 32 + sg];
            #pragma unroll
            for (int mi = 0; mi < 2; mi++)
                #pragma unroll
                for (int nj = 0; nj < 4; nj++)
                    acc[mi][nj] = MFMA16(af[mi], bfr[nj], acc[mi][nj]);
        }
    }

    // ---- epilogue: LDS transpose [n][m] -> 16B stores dense in t ----
    short* tr = SMEM;                    // [128][72] = 9216 shorts
    __syncthreads();
    #pragma unroll
    for (int nj = 0; nj < 4; nj++) {
        int nl = wn * 64 + nj * 16 + lm;     // 0..127
        float bv = bias[n0 + nl];
        #pragma unroll
        for (int mi = 0; mi < 2; mi++) {
            #pragma unroll
            for (int r = 0; r < 4; r++) {
                int ml = wm * 32 + mi * 16 + lq * 4 + r;   // 0..63
                tr[nl * 72 + ml] = (short)f2b(acc[mi][nj][r] + bv);
            }
        }
    }
    __syncthreads();
    #pragma unroll
    for (int i = 0; i < 4; i++) {
        int g  = i * 256 + tid;          // 0..1023
        int nl = g >> 3;                 // 0..127
        int mc = (g & 7) * 8;            // 0..56
        s16x8 vv = *(const s16x8*)&tr[nl * 72 + mc];
        int n = n0 + nl, m = m0 + mc;
        int h = n >> 6, d = n & (D_ - 1);
        int bb = m >> 11, t = m & (T_ - 1);
        *(s16x8*)&VT[(((size_t)bb * H_ + h) * D_ + d) * T_ + t] = vv;
    }
#undef V_ASH
#undef V_BSH
}

// ---------------------------------------------------------------------------
// proj: out fp32 [M,C] = Yb(bf16) @ WpT(bf16) + bias. 64x128 tile, XCD
// remap, BK=64 panels, LDS 24 KB. (R24; fp32 row-major out already coalesced)
// ---------------------------------------------------------------------------
__global__ __launch_bounds__(256, 4) void proj_mfma(
    const short* __restrict__ Ah, const short* __restrict__ BTh,
    const float* __restrict__ bias, float* __restrict__ out)
{
    __shared__ short Ash[2][64 * 32];
    __shared__ short Bsh[2][128 * 32];

    const int tid  = threadIdx.x;
    const int wave = tid >> 6, lane = tid & 63;
    const int wm = wave >> 1, wn = wave & 1;
    const int lm = lane & 15, lq = lane >> 4;
    const int fid = blockIdx.y * 8 + blockIdx.x;
    const int wg  = (fid & 7) * 64 + (fid >> 3);
    const int n0  = (wg & 7) * 128;
    const int m0  = (wg >> 3) * 64;
    const int gr  = (lane >> 2);
    const int gc  = (((lane & 3) ^ ((lane >> 3) & 3)) << 3);
    const int sg  = ((lq ^ ((lm >> 1) & 3)) << 3);

    f32x4 acc[2][4] = {};

    for (int k0 = 0; k0 < C_; k0 += 64) {
        __syncthreads();
        #pragma unroll
        for (int p = 0; p < 2; p++) {
            int kp = k0 + p * 32;
            int rowA = wave * 16 + gr;
            gload_lds16(&Ah[(size_t)(m0 + rowA) * C_ + kp + gc], &Ash[p][wave * 512]);
            #pragma unroll
            for (int j = 0; j < 2; j++) {
                int s = wave * 2 + j;
                int rowB = s * 16 + gr;
                gload_lds16(&BTh[(size_t)(n0 + rowB) * C_ + kp + gc], &Bsh[p][s * 512]);
            }
        }
        __syncthreads();

        #pragma unroll
        for (int p = 0; p < 2; p++) {
            s16x8 af[2], bfr[4];
            #pragma unroll
            for (int mi = 0; mi < 2; mi++)
                af[mi] = *(const s16x8*)&Ash[p][(wm * 32 + mi * 16 + lm) * 32 + sg];
            #pragma unroll
            for (int nj = 0; nj < 4; nj++)
                bfr[nj] = *(const s16x8*)&Bsh[p][(wn * 64 + nj * 16 + lm) * 32 + sg];
            #pragma unroll
            for (int mi = 0; mi < 2; mi++)
                #pragma unroll
                for (int nj = 0; nj < 4; nj++)
                    acc[mi][nj] = MFMA16(af[mi], bfr[nj], acc[mi][nj]);
        }
    }

    #pragma unroll
    for (int nj = 0; nj < 4; nj++) {
        int n = n0 + wn * 64 + nj * 16 + lm;
        float bv = bias[n];
        #pragma unroll
        for (int mi = 0; mi < 2; mi++) {
            #pragma unroll
            for (int r = 0; r < 4; r++) {
                int m = m0 + wm * 32 + mi * 16 + lq * 4 + r;
                out[(size_t)m * C_ + n] = acc[mi][nj][r] + bv;
            }
        }
    }
}

// ---------------------------------------------------------------------------
// online softmax (exp2 domain) with defer-max (THR=8). S in/out: S^T frag,
// per-thread 16 values for q-row lm. On exit S holds P = exp2(S - m).
// ---------------------------------------------------------------------------
__device__ __forceinline__ void online_sm(
    f32x4 S[4], float& mrow, float& lrow, f32x4 O[4], int quad)
{
    float v[16];
    #pragma unroll
    for (int t = 0; t < 4; t++)
        #pragma unroll
        for (int r = 0; r < 4; r++) v[t * 4 + r] = S[t][r];
    #pragma unroll
    for (int s = 8; s; s >>= 1)
        #pragma unroll
        for (int i = 0; i < s; i++) v[i] = fmaxf(v[i], v[i + s]);
    float rm = v[0];
    rm = fmaxf(rm, __shfl_xor(rm, 16, 64));
    rm = fmaxf(rm, __shfl_xor(rm, 32, 64));
    // defer-max: only rescale when some row grew by > 8 (=2^8 headroom)
    if (!__all(rm - mrow <= 8.f)) {
        float mnew  = fmaxf(mrow, rm);
        float alpha = fexp2(mrow - mnew);
        mrow = mnew;
        lrow *= alpha;
        float al[4];
        #pragma unroll
        for (int r = 0; r < 4; r++) al[r] = __shfl(alpha, quad * 4 + r, 64);
        #pragma unroll
        for (int t = 0; t < 4; t++)
            #pragma unroll
            for (int r = 0; r < 4; r++) O[t][r] *= al[r];
    }
    float sv[16];
    #pragma unroll
    for (int t = 0; t < 4; t++)
        #pragma unroll
        for (int r = 0; r < 4; r++) {
            float p = fexp2(S[t][r] - mrow);
            S[t][r] = p;
            sv[t * 4 + r] = p;
        }
    #pragma unroll
    for (int s = 8; s; s >>= 1)
        #pragma unroll
        for (int i = 0; i < s; i++) sv[i] += sv[i + s];
    float rs = sv[0];
    rs += __shfl_xor(rs, 16, 64);
    rs += __shfl_xor(rs, 32, 64);
    lrow += rs;
}

// ---------------------------------------------------------------------------
// MFMA flash attention, S^T layout, PAIRED q-tiles per block. Grid 512.
// NEW: K/V LDS double-buffered, ONE __syncthreads per iteration; LDS-write
// of tile kt+1 and global-load issue of tile kt+2 overlap compute(buf[cur]).
// LDS 64KB (2 blocks/CU), XOR-swizzled, setprio, exp2 defer-max softmax.
// ---------------------------------------------------------------------------
__global__ __launch_bounds__(256, 2) void attn_mfma(
    const short* __restrict__ Qh, const short* __restrict__ Ql,
    const short* __restrict__ Kh, const short* __restrict__ Kl,
    const short* __restrict__ VT, short* __restrict__ Yb)
{
    __shared__ short Ksh[2][64][64], Ksl[2][64][64];   // [buf][key][d]
    __shared__ short Vt [2][64][64];                   // [buf][d][key]
    __shared__ short Ps [4][2][16][64];                // per-wave P slabs

    const int tid  = threadIdx.x;
    const int wave = tid >> 6, lane = tid & 63;
    const int lm   = lane & 15, quad = lane >> 4;
    const int swz  = (lm & 7) << 3;              // read-side XOR (shorts)

    const int bid = blockIdx.x;                  // 512 blocks
    const int xcd = bid & 7;
    const int r_  = bid >> 3;                    // 0..63 per XCD
    const int bhl = r_ & 3;
    const int u   = r_ >> 2;                     // 0..15
    const int g_  = u >> 3, j_ = u & 7;
    const int j   = g_ ? (15 - j_) : j_;         // CU slot pairs j with 15-j
    const int bh  = xcd * 4 + bhl;
    const int b   = bh >> 4, h = bh & (H_ - 1);
    const int qtA = j, qtB = 31 - j;
    const int q0A = qtA * 64, q0B = qtB * 64;
    const size_t base  = (size_t)bh * T_ * D_;   // Q,K: [b,h,t,d]
    const size_t vbase = (size_t)bh * D_ * T_;   // VT:  [b,h,d,t]

    const int src = tid >> 3;                    // staging row 0..31 (+32)
    const int sch = (tid & 7) * 8;               // linear global col (shorts)
    const int wsw = sch ^ ((src & 7) << 3);      // swizzled LDS write col

    // ---- Q frags direct from global (L2-hit, once per block) ----
    s16x8 bqhA[2], bqlA[2], bqhB[2], bqlB[2];
    #pragma unroll
    for (int kc = 0; kc < 2; kc++) {
        size_t ga = base + (size_t)(q0A + wave * 16 + lm) * D_ + kc * 32 + quad * 8;
        size_t gb = base + (size_t)(q0B + wave * 16 + lm) * D_ + kc * 32 + quad * 8;
        bqhA[kc] = *(const s16x8*)&Qh[ga];
        bqlA[kc] = *(const s16x8*)&Ql[ga];
        bqhB[kc] = *(const s16x8*)&Qh[gb];
        bqlB[kc] = *(const s16x8*)&Ql[gb];
    }

    // ---- prologue: tile 0 -> regs -> buf0; issue tile 1 loads ----
    s16x8 pkh[2], pkl[2], pvt[2];
    #pragma unroll
    for (int i = 0; i < 2; i++) {
        int row = i * 32 + src;
        size_t gk = base + (size_t)row * D_ + sch;
        pkh[i] = *(const s16x8*)&Kh[gk];
        pkl[i] = *(const s16x8*)&Kl[gk];
        pvt[i] = *(const s16x8*)&VT[vbase + (size_t)row * T_ + sch];
    }
    #pragma unroll
    for (int i = 0; i < 2; i++) {
        int row = i * 32 + src;
        *(s16x8*)&Ksh[0][row][wsw] = pkh[i];
        *(s16x8*)&Ksl[0][row][wsw] = pkl[i];
        *(s16x8*)&Vt [0][row][wsw] = pvt[i];
    }
    {   // qtB >= 16, so tile 1 always exists
        #pragma unroll
        for (int i = 0; i < 2; i++) {
            int row = i * 32 + src;
            size_t gk = base + (size_t)(64 + row) * D_ + sch;
            pkh[i] = *(const s16x8*)&Kh[gk];
            pkl[i] = *(const s16x8*)&Kl[gk];
            pvt[i] = *(const s16x8*)&VT[vbase + (size_t)row * T_ + 64 + sch];
        }
    }
    __syncthreads();

    float mA = -INFINITY, lA = 0.f;
    float mB = -INFINITY, lB = 0.f;
    f32x4 OA[4] = {}, OB[4] = {};

    for (int kt = 0; kt <= qtB; kt++) {
        const int cur = kt & 1;

        // ---- write tile kt+1 -> buf[cur^1]; issue loads for kt+2 ----
        // (overlaps compute below; drained by end-of-iter __syncthreads)
        if (kt < qtB) {
            #pragma unroll
            for (int i = 0; i < 2; i++) {
                int row = i * 32 + src;
                *(s16x8*)&Ksh[cur ^ 1][row][wsw] = pkh[i];
                *(s16x8*)&Ksl[cur ^ 1][row][wsw] = pkl[i];
                *(s16x8*)&Vt [cur ^ 1][row][wsw] = pvt[i];
            }
            if (kt + 2 <= qtB) {
                #pragma unroll
                for (int i = 0; i < 2; i++) {
                    int row = i * 32 + src;
                    size_t gk = base + (size_t)((kt + 2) * 64 + row) * D_ + sch;
                    pkh[i] = *(const s16x8*)&Kh[gk];
                    pkl[i] = *(const s16x8*)&Kl[gk];
                    pvt[i] = *(const s16x8*)&VT[vbase + (size_t)row * T_ + (kt + 2) * 64 + sch];
                }
            }
        }

        const bool doA = (kt <= qtA);
        const int  qg  = wave * 16 + lm;

        f32x4 SB[4] = {}, SA[4] = {};
        __builtin_amdgcn_s_setprio(1);
        if (doA) {
            // dual: one k-frag read feeds 6 MFMAs (two independent chains)
            #pragma unroll
            for (int t = 0; t < 4; t++)
                #pragma unroll
                for (int kc = 0; kc < 2; kc++) {
                    s16x8 kh8 = *(const s16x8*)&Ksh[cur][t * 16 + lm][(kc * 32 + quad * 8) ^ swz];
                    s16x8 kl8 = *(const s16x8*)&Ksl[cur][t * 16 + lm][(kc * 32 + quad * 8) ^ swz];
                    SB[t] = MFMA16(kh8, bqhB[kc], SB[t]);
                    SB[t] = MFMA16(kl8, bqhB[kc], SB[t]);
                    SB[t] = MFMA16(kh8, bqlB[kc], SB[t]);
                    SA[t] = MFMA16(kh8, bqhA[kc], SA[t]);
                    SA[t] = MFMA16(kl8, bqhA[kc], SA[t]);
                    SA[t] = MFMA16(kh8, bqlA[kc], SA[t]);
                }
        } else {
            #pragma unroll
            for (int t = 0; t < 4; t++)
                #pragma unroll
                for (int kc = 0; kc < 2; kc++) {
                    s16x8 kh8 = *(const s16x8*)&Ksh[cur][t * 16 + lm][(kc * 32 + quad * 8) ^ swz];
                    s16x8 kl8 = *(const s16x8*)&Ksl[cur][t * 16 + lm][(kc * 32 + quad * 8) ^ swz];
                    SB[t] = MFMA16(kh8, bqhB[kc], SB[t]);
                    SB[t] = MFMA16(kl8, bqhB[kc], SB[t]);
                    SB[t] = MFMA16(kh8, bqlB[kc], SB[t]);
                }
        }
        __builtin_amdgcn_s_setprio(0);

        // causal masks (scale pre-folded into Q)
        if (kt == qtB) {
            #pragma unroll
            for (int t = 0; t < 4; t++)
                #pragma unroll
                for (int r = 0; r < 4; r++)
                    if ((t * 16 + quad * 4 + r) > qg) SB[t][r] = -INFINITY;
        }
        if (kt == qtA) {
            #pragma unroll
            for (int t = 0; t < 4; t++)
                #pragma unroll
                for (int r = 0; r < 4; r++)
                    if ((t * 16 + quad * 4 + r) > qg) SA[t][r] = -INFINITY;
        }

        // ---- softmax (dual chains are independent) ----
        online_sm(SB, mB, lB, OB, quad);
        if (doA) online_sm(SA, mA, lA, OA, quad);

        // ---- P^T -> Ps (truncating bf16; P in [0, 256]) ----
        #pragma unroll
        for (int t = 0; t < 4; t++) {
            s16x4 p;
            #pragma unroll
            for (int r = 0; r < 4; r++)
                p[r] = (short)(__float_as_uint(SB[t][r]) >> 16);
            *(s16x4*)&Ps[wave][0][lm][(t * 16 + quad * 4) ^ swz] = p;
        }
        if (doA) {
            #pragma unroll
            for (int t = 0; t < 4; t++) {
                s16x4 p;
                #pragma unroll
                for (int r = 0; r < 4; r++)
                    p[r] = (short)(__float_as_uint(SA[t][r]) >> 16);
                *(s16x4*)&Ps[wave][1][lm][(t * 16 + quad * 4) ^ swz] = p;
            }
        }
        // wave-private slabs: no barrier (lgkmcnt ordering within wave)

        // ---- O += P V: shared Vt frag feeds both tiles ----
        s16x8 apB[2], apA[2];
        #pragma unroll
        for (int kc = 0; kc < 2; kc++)
            apB[kc] = *(const s16x8*)&Ps[wave][0][lm][(kc * 32 + quad * 8) ^ swz];
        __builtin_amdgcn_s_setprio(1);
        if (doA) {
            #pragma unroll
            for (int kc = 0; kc < 2; kc++)
                apA[kc] = *(const s16x8*)&Ps[wave][1][lm][(kc * 32 + quad * 8) ^ swz];
            #pragma unroll
            for (int t = 0; t < 4; t++)
                #pragma unroll
                for (int kc = 0; kc < 2; kc++) {
                    s16x8 bv = *(const s16x8*)&Vt[cur][t * 16 + lm][(kc * 32 + quad * 8) ^ swz];
                    OB[t] = MFMA16(apB[kc], bv, OB[t]);
                    OA[t] = MFMA16(apA[kc], bv, OA[t]);
                }
        } else {
            #pragma unroll
            for (int t = 0; t < 4; t++)
                #pragma unroll
                for (int kc = 0; kc < 2; kc++) {
                    s16x8 bv = *(const s16x8*)&Vt[cur][t * 16 + lm][(kc * 32 + quad * 8) ^ swz];
                    OB[t] = MFMA16(apB[kc], bv, OB[t]);
                }
        }
        __builtin_amdgcn_s_setprio(0);

        __syncthreads();   // reads of buf[cur] done; writes of buf[cur^1] visible
    }

    // ---- epilogue: O row q = wave*16+quad*4+r, col d = t*16+lm ----
    float liA[4], liB[4];
    #pragma unroll
    for (int r = 0; r < 4; r++) {
        liA[r] = 1.0f / __shfl(lA, quad * 4 + r, 64);
        liB[r] = 1.0f / __shfl(lB, quad * 4 + r, 64);
    }
    #pragma unroll
    for (int t = 0; t < 4; t++)
        #pragma unroll
        for (int r = 0; r < 4; r++) {
            int d  = t * 16 + lm;
            int qa = q0A + wave * 16 + quad * 4 + r;
            int qb = q0B + wave * 16 + quad * 4 + r;
            Yb[((size_t)b * T_ + qa) * C_ + h * D_ + d] =
                (short)f2b(OA[t][r] * liA[r]);
            Yb[((size_t)b * T_ + qb) * C_ + h * D_ + d] =
                (short)f2b(OB[t][r] * liB[r]);
        }
}

// ---------------------------------------------------------------------------
extern "C" void kernel_launch(void* const* d_in, const int* in_sizes, int n_in,
                              void* d_out, int out_size, void* d_ws, size_t ws_size,
                              hipStream_t stream)
{
    const float* x      = (const float*)d_in[0];
    const float* W_attn = (const float*)d_in[1];
    const float* b_attn = (const float*)d_in[2];
    const float* W_proj = (const float*)d_in[3];
    const float* b_proj = (const float*)d_in[4];
    float* out = (float*)d_out;

    char* ws = (char*)d_ws;
    const size_t MB = 1024 * 1024;
    short* Qh   = (short*)(ws);            // 8 MB  [ 0, 8)
    short* Ql   = (short*)(ws +  8 * MB);  // 8 MB  [ 8,16)
    short* Kh   = (short*)(ws + 16 * MB);  // 8 MB  [16,24)
    short* Kl   = (short*)(ws + 24 * MB);  // 8 MB  [24,32)
    short* xh   = (short*)(ws + 32 * MB);  // 8 MB  [32,40)  dead after qkv_v
    short* xl   = (short*)(ws + 40 * MB);  // 8 MB  [40,48)  dead after qkv_qk
    short* WaTh = (short*)(ws + 48 * MB);  // 6 MB  [48,54)
    short* WaTl = (short*)(ws + 54 * MB);  // 6 MB  [54,60)
    short* WpT  = (short*)(ws + 60 * MB);  // 2 MB  [60,62)
    short* VT   = (short*)(ws + 40 * MB);  // 8 MB  aliases xl (born at qkv_v)
    short* Yb   = (short*)(ws + 32 * MB);  // 8 MB  aliases xh (born at attn)

    cvt_all<<<dim3(3072), 256, 0, stream>>>(x, xh, xl, W_attn, WaTh, WaTl,
                                            W_proj, WpT);

    qkv_qk <<<dim3(16, 32), 256, 0, stream>>>(xh, xl, WaTh, WaTl, b_attn,
                                              Qh, Ql, Kh, Kl);
    qkv_v  <<<dim3(8, 64), 256, 0, stream>>>(xh, WaTh + (size_t)2048 * C_,
                                             b_attn + 2048, VT);
    attn_mfma<<<dim3(512), 256, 0, stream>>>(Qh, Ql, Kh, Kl, VT, Yb);
    proj_mfma<<<dim3(8, 64), 256, 0, stream>>>(Yb, WpT, b_proj, out);
}

// Round 17
// 222.687 us; speedup vs baseline: 1.1081x; 1.0326x over previous
//
#include <hip/hip_runtime.h>
#include <hip/hip_bf16.h>

// Problem: CausalSelfAttention  B=2, T=2048, C=1024, H=16, D=64
// Round 29: attn softmax-sum via MFMA (+max3 tree). R28 = best (229.9;
// single-barrier dbuf confirmed, attn 59.2 sole top, VALU 35 > Mfma 23).
// The P row-sum (16 acc + 15 add + 2 shfl per chain per iter, pure VALU)
// is a free matrix-pipe op: l[q] = mfma(P, ones) -- output layout
// C[row=quad*4+r] lands exactly in epilogue li[r] (kills final shfl too).
// l now sums the SAME bf16-truncated P that PV uses (exact normalization
// of truncated P; shift ~1e-3 rel, 3x absmax headroom). Max tree 15 ->
// ~10 ops via v_max3 fusion (fmaxf nesting). ~70 VALU/iter saved, +4 MFMA
// on a 23%-busy pipe. All else byte-identical to R28.
// ws (62 MB): Qh 8|Ql 8|Kh 8|Kl 8|xh 8(->Yb)|xl 8(->VT)|WaTh 6|WaTl 6|WpT 2

#define B_  2
#define T_  2048
#define C_  1024
#define H_  16
#define D_  64
#define M_  (B_ * T_)      // 4096
#define N3_ (3 * C_)       // 3072

typedef __attribute__((ext_vector_type(8))) short s16x8;
typedef __attribute__((ext_vector_type(4))) short s16x4;
typedef __attribute__((ext_vector_type(4))) float f32x4;

typedef const __attribute__((address_space(1))) unsigned int gu32_t;
typedef __attribute__((address_space(3))) unsigned int lu32_t;

#define MFMA16(a, b, c) __builtin_amdgcn_mfma_f32_16x16x32_bf16(a, b, c, 0, 0, 0)

__device__ __forceinline__ void gload_lds16(const short* g, short* l) {
    __builtin_amdgcn_global_load_lds((gu32_t*)g, (lu32_t*)l, 16, 0, 0);
}

__device__ __forceinline__ float b2f(unsigned short u) {
    return __uint_as_float(((unsigned)u) << 16);
}
__device__ __forceinline__ unsigned short f2b(float f) {   // RNE bf16 round
    unsigned u = __float_as_uint(f);
    return (unsigned short)((u + 0x7FFFu + ((u >> 16) & 1u)) >> 16);
}
__device__ __forceinline__ float fexp2(float x) {
#if __has_builtin(__builtin_amdgcn_exp2f)
    return __builtin_amdgcn_exp2f(x);
#else
    return exp2f(x);
#endif
}

// ---------------------------------------------------------------------------
// cvt_all: one dispatch for all input conversions (grid 3072).
// ---------------------------------------------------------------------------
__global__ __launch_bounds__(256) void cvt_all(
    const float* __restrict__ x,  short* __restrict__ xh,   short* __restrict__ xl,
    const float* __restrict__ Wa, short* __restrict__ WaTh, short* __restrict__ WaTl,
    const float* __restrict__ Wp, short* __restrict__ WpT)
{
    __shared__ short th[64][80];
    __shared__ short tl[64][80];
    const int tid = threadIdx.x;
    const int bid = blockIdx.x;

    if (bid < 2048) {
        int i = (bid * 256 + tid) * 8;
        float4 a = *(const float4*)&x[i];
        float4 b = *(const float4*)&x[i + 4];
        float v[8] = {a.x, a.y, a.z, a.w, b.x, b.y, b.z, b.w};
        s16x8 h, l;
        #pragma unroll
        for (int j = 0; j < 8; j++) {
            unsigned short hb = f2b(v[j]);
            h[j] = (short)hb;
            l[j] = (short)f2b(v[j] - b2f(hb));
        }
        *(s16x8*)&xh[i] = h;
        *(s16x8*)&xl[i] = l;
        return;
    }

    if (bid < 2816) {
        int r  = bid - 2048;            // 0..767
        int bx = r % 48, by = r / 48;   // (N3_/64, C_/64)
        const int k0 = by * 64, n0 = bx * 64;
        const int R = C_, Cn = N3_;
        {
            int rl = tid >> 4, cl = (tid & 15) * 4;
            #pragma unroll
            for (int i = 0; i < 4; i++) {
                int kr = rl + i * 16;
                float4 v4 = *(const float4*)&Wa[(size_t)(k0 + kr) * Cn + n0 + cl];
                float v[4] = {v4.x, v4.y, v4.z, v4.w};
                #pragma unroll
                for (int j = 0; j < 4; j++) {
                    unsigned short hb = f2b(v[j]);
                    th[cl + j][kr] = (short)hb;
                    tl[cl + j][kr] = (short)f2b(v[j] - b2f(hb));
                }
            }
        }
        __syncthreads();
        {
            int ro = tid >> 2, co = (tid & 3) * 16;
            *(s16x8*)&WaTh[(size_t)(n0 + ro) * R + k0 + co]     = *(s16x8*)&th[ro][co];
            *(s16x8*)&WaTh[(size_t)(n0 + ro) * R + k0 + co + 8] = *(s16x8*)&th[ro][co + 8];
            *(s16x8*)&WaTl[(size_t)(n0 + ro) * R + k0 + co]     = *(s16x8*)&tl[ro][co];
            *(s16x8*)&WaTl[(size_t)(n0 + ro) * R + k0 + co + 8] = *(s16x8*)&tl[ro][co + 8];
        }
        return;
    }

    {
        int r  = bid - 2816;            // 0..255
        int bx = r & 15, by = r >> 4;   // (C_/64, C_/64)
        const int k0 = by * 64, n0 = bx * 64;
        const int R = C_, Cn = C_;
        {
            int rl = tid >> 4, cl = (tid & 15) * 4;
            #pragma unroll
            for (int i = 0; i < 4; i++) {
                int kr = rl + i * 16;
                float4 v = *(const float4*)&Wp[(size_t)(k0 + kr) * Cn + n0 + cl];
                th[cl + 0][kr] = (short)f2b(v.x);
                th[cl + 1][kr] = (short)f2b(v.y);
                th[cl + 2][kr] = (short)f2b(v.z);
                th[cl + 3][kr] = (short)f2b(v.w);
            }
        }
        __syncthreads();
        {
            int ro = tid >> 2, co = (tid & 3) * 16;
            *(s16x8*)&WpT[(size_t)(n0 + ro) * R + k0 + co]     = *(s16x8*)&th[ro][co];
            *(s16x8*)&WpT[(size_t)(n0 + ro) * R + k0 + co + 8] = *(s16x8*)&th[ro][co + 8];
        }
    }
}

// ---------------------------------------------------------------------------
// qkv_qk: Q,K columns (N=2048), bf16x3, hi/lo. 128x128 tile, XCD remap,
// BK=64 panels, LDS 64 KB (merged SMEM), 0-conflict granule swizzle.
// Epilogue stages tile through LDS [128][136] -> 16B coalesced stores. (R27)
// ---------------------------------------------------------------------------
__global__ __launch_bounds__(256) void qkv_qk(
    const short* __restrict__ Ah, const short* __restrict__ Al,
    const short* __restrict__ BTh, const short* __restrict__ BTl,
    const float* __restrict__ bias,
    short* __restrict__ Qh, short* __restrict__ Ql,
    short* __restrict__ Kh, short* __restrict__ Kl)
{
    __shared__ short SMEM[32768];   // 64 KB: Ash|Asl|Bsh|Bsl, 2-buf each
#define QK_ASH(p) (&SMEM[(p) * 4096])
#define QK_ASL(p) (&SMEM[8192 + (p) * 4096])
#define QK_BSH(p) (&SMEM[16384 + (p) * 4096])
#define QK_BSL(p) (&SMEM[24576 + (p) * 4096])

    const int tid  = threadIdx.x;
    const int wave = tid >> 6, lane = tid & 63;
    const int wm = wave >> 1, wn = wave & 1;
    const int lm = lane & 15, lq = lane >> 4;
    const int fid = blockIdx.y * 16 + blockIdx.x;
    const int wg  = (fid & 7) * 64 + (fid >> 3);
    const int n0  = (wg & 15) * 128;
    const int m0  = (wg >> 4) * 128;
    const int gr  = (lane >> 2);
    const int gc  = (((lane & 3) ^ ((lane >> 3) & 3)) << 3);
    const int sg  = ((lq ^ ((lm >> 1) & 3)) << 3);

    f32x4 acc[4][4] = {};

    for (int k0 = 0; k0 < C_; k0 += 64) {
        __syncthreads();
        #pragma unroll
        for (int p = 0; p < 2; p++) {
            int kp = k0 + p * 32;
            #pragma unroll
            for (int j = 0; j < 2; j++) {
                int s = wave * 2 + j;
                int row = s * 16 + gr;
                size_t ga = (size_t)(m0 + row) * C_ + kp + gc;
                size_t gb = (size_t)(n0 + row) * C_ + kp + gc;
                gload_lds16(&Ah[ga],  QK_ASH(p) + s * 512);
                gload_lds16(&Al[ga],  QK_ASL(p) + s * 512);
                gload_lds16(&BTh[gb], QK_BSH(p) + s * 512);
                gload_lds16(&BTl[gb], QK_BSL(p) + s * 512);
            }
        }
        __syncthreads();

        #pragma unroll
        for (int p = 0; p < 2; p++) {
            s16x8 ah[4], al[4], bh[4], bl[4];
            #pragma unroll
            for (int mi = 0; mi < 4; mi++) {
                int r = wm * 64 + mi * 16 + lm;
                ah[mi] = *(const s16x8*)&QK_ASH(p)[r * 32 + sg];
                al[mi] = *(const s16x8*)&QK_ASL(p)[r * 32 + sg];
            }
            #pragma unroll
            for (int nj = 0; nj < 4; nj++) {
                int r = wn * 64 + nj * 16 + lm;
                bh[nj] = *(const s16x8*)&QK_BSH(p)[r * 32 + sg];
                bl[nj] = *(const s16x8*)&QK_BSL(p)[r * 32 + sg];
            }
            #pragma unroll
            for (int mi = 0; mi < 4; mi++)
                #pragma unroll
                for (int nj = 0; nj < 4; nj++) {
                    acc[mi][nj] = MFMA16(ah[mi], bh[nj], acc[mi][nj]);
                    acc[mi][nj] = MFMA16(ah[mi], bl[nj], acc[mi][nj]);
                    acc[mi][nj] = MFMA16(al[mi], bh[nj], acc[mi][nj]);
                }
        }
    }

    // ---- epilogue: LDS transpose -> coalesced 16B stores (hi, then lo) ----
    short* tr = SMEM;   // [128][136] bf16
    #pragma unroll
    for (int pass = 0; pass < 2; pass++) {
        __syncthreads();                 // staging (or prev pass reads) done
        #pragma unroll
        for (int nj = 0; nj < 4; nj++) {
            int nl = wn * 64 + nj * 16 + lm;
            int n  = n0 + nl;
            float bv = bias[n];
            // Q carries sqrt(D)=8 and log2(e): softmax runs in exp2 domain
            float scale = (n >> 10) ? 1.0f : 11.541560327111708f;
            #pragma unroll
            for (int mi = 0; mi < 4; mi++) {
                #pragma unroll
                for (int r = 0; r < 4; r++) {
                    int ml = wm * 64 + mi * 16 + lq * 4 + r;
                    float v = (acc[mi][nj][r] + bv) * scale;
                    unsigned short hb = f2b(v);
                    unsigned short val = (pass == 0) ? hb
                                       : f2b(v - b2f(hb));
                    tr[ml * 136 + nl] = (short)val;
                }
            }
        }
        __syncthreads();
        #pragma unroll
        for (int i = 0; i < 8; i++) {
            int g  = i * 256 + tid;          // 0..2047
            int ml = g >> 4;                 // 0..127
            int nc = (g & 15) * 8;           // 0..120
            s16x8 vv = *(const s16x8*)&tr[ml * 136 + nc];
            int m = m0 + ml, n = n0 + nc;
            int isK = n >> 10;
            int c = n & (C_ - 1);
            int h = c >> 6, d = c & (D_ - 1);
            int bb = m >> 11, t = m & (T_ - 1);
            short* dst = (pass == 0) ? (isK ? Kh : Qh) : (isK ? Kl : Ql);
            *(s16x8*)&dst[(((size_t)bb * H_ + h) * T_ + t) * D_ + d] = vv;
        }
    }
#undef QK_ASH
#undef QK_ASL
#undef QK_BSH
#undef QK_BSL
}

// ---------------------------------------------------------------------------
// qkv_v: V columns (N=1024), single bf16 -> VT [B,H,D,T]. 64x128 tile, XCD
// remap, BK=64 panels, LDS 24 KB (merged). Epilogue stages through LDS
// [128][72] -> 16B stores dense in t. (R27)
// ---------------------------------------------------------------------------
__global__ __launch_bounds__(256, 4) void qkv_v(
    const short* __restrict__ Ah, const short* __restrict__ BTh,
    const float* __restrict__ bias, short* __restrict__ VT)
{
    __shared__ short SMEM[12288];   // 24 KB: Ash(2x2048) | Bsh(2x4096)
#define V_ASH(p) (&SMEM[(p) * 2048])
#define V_BSH(p) (&SMEM[4096 + (p) * 4096])

    const int tid  = threadIdx.x;
    const int wave = tid >> 6, lane = tid & 63;
    const int wm = wave >> 1, wn = wave & 1;
    const int lm = lane & 15, lq = lane >> 4;
    const int fid = blockIdx.y * 8 + blockIdx.x;
    const int wg  = (fid & 7) * 64 + (fid >> 3);
    const int n0  = (wg & 7) * 128;
    const int m0  = (wg >> 3) * 64;
    const int gr  = (lane >> 2);
    const int gc  = (((lane & 3) ^ ((lane >> 3) & 3)) << 3);
    const int sg  = ((lq ^ ((lm >> 1) & 3)) << 3);

    f32x4 acc[2][4] = {};

    for (int k0 = 0; k0 < C_; k0 += 64) {
        __syncthreads();
        #pragma unroll
        for (int p = 0; p < 2; p++) {
            int kp = k0 + p * 32;
            int rowA = wave * 16 + gr;
            gload_lds16(&Ah[(size_t)(m0 + rowA) * C_ + kp + gc], V_ASH(p) + wave * 512);
            #pragma unroll
            for (int j = 0; j < 2; j++) {
                int s = wave * 2 + j;
                int rowB = s * 16 + gr;
                gload_lds16(&BTh[(size_t)(n0 + rowB) * C_ + kp + gc], V_BSH(p) + s * 512);
            }
        }
        __syncthreads();

        #pragma unroll
        for (int p = 0; p < 2; p++) {
            s16x8 af[2], bfr[4];
            #pragma unroll
            for (int mi = 0; mi < 2; mi++)
                af[mi] = *(const s16x8*)&V_ASH(p)[(wm * 32 + mi * 16 + lm) * 32 + sg];
            #pragma unroll
            for (int nj = 0; nj < 4; nj++)
                bfr[nj] = *(const s16x8*)&V_BSH(p)[(wn * 64 + nj * 16 + lm) * 32 + sg];
            #pragma unroll
            for (int mi = 0; mi < 2; mi++)
                #pragma unroll
                for (int nj = 0; nj < 4; nj++)
                    acc[mi][nj] = MFMA16(af[mi], bfr[nj], acc[mi][nj]);
        }
    }

    // ---- epilogue: LDS transpose [n][m] -> 16B stores dense in t ----
    short* tr = SMEM;                    // [128][72] = 9216 shorts
    __syncthreads();
    #pragma unroll
    for (int nj = 0; nj < 4; nj++) {
        int nl = wn * 64 + nj * 16 + lm;     // 0..127
        float bv = bias[n0 + nl];
        #pragma unroll
        for (int mi = 0; mi < 2; mi++) {
            #pragma unroll
            for (int r = 0; r < 4; r++) {
                int ml = wm * 32 + mi * 16 + lq * 4 + r;   // 0..63
                tr[nl * 72 + ml] = (short)f2b(acc[mi][nj][r] + bv);
            }
        }
    }
    __syncthreads();
    #pragma unroll
    for (int i = 0; i < 4; i++) {
        int g  = i * 256 + tid;          // 0..1023
        int nl = g >> 3;                 // 0..127
        int mc = (g & 7) * 8;            // 0..56
        s16x8 vv = *(const s16x8*)&tr[nl * 72 + mc];
        int n = n0 + nl, m = m0 + mc;
        int h = n >> 6, d = n & (D_ - 1);
        int bb = m >> 11, t = m & (T_ - 1);
        *(s16x8*)&VT[(((size_t)bb * H_ + h) * D_ + d) * T_ + t] = vv;
    }
#undef V_ASH
#undef V_BSH
}

// ---------------------------------------------------------------------------
// proj: out fp32 [M,C] = Yb(bf16) @ WpT(bf16) + bias. 64x128 tile, XCD
// remap, BK=64 panels, LDS 24 KB. (R24)
// ---------------------------------------------------------------------------
__global__ __launch_bounds__(256, 4) void proj_mfma(
    const short* __restrict__ Ah, const short* __restrict__ BTh,
    const float* __restrict__ bias, float* __restrict__ out)
{
    __shared__ short Ash[2][64 * 32];
    __shared__ short Bsh[2][128 * 32];

    const int tid  = threadIdx.x;
    const int wave = tid >> 6, lane = tid & 63;
    const int wm = wave >> 1, wn = wave & 1;
    const int lm = lane & 15, lq = lane >> 4;
    const int fid = blockIdx.y * 8 + blockIdx.x;
    const int wg  = (fid & 7) * 64 + (fid >> 3);
    const int n0  = (wg & 7) * 128;
    const int m0  = (wg >> 3) * 64;
    const int gr  = (lane >> 2);
    const int gc  = (((lane & 3) ^ ((lane >> 3) & 3)) << 3);
    const int sg  = ((lq ^ ((lm >> 1) & 3)) << 3);

    f32x4 acc[2][4] = {};

    for (int k0 = 0; k0 < C_; k0 += 64) {
        __syncthreads();
        #pragma unroll
        for (int p = 0; p < 2; p++) {
            int kp = k0 + p * 32;
            int rowA = wave * 16 + gr;
            gload_lds16(&Ah[(size_t)(m0 + rowA) * C_ + kp + gc], &Ash[p][wave * 512]);
            #pragma unroll
            for (int j = 0; j < 2; j++) {
                int s = wave * 2 + j;
                int rowB = s * 16 + gr;
                gload_lds16(&BTh[(size_t)(n0 + rowB) * C_ + kp + gc], &Bsh[p][s * 512]);
            }
        }
        __syncthreads();

        #pragma unroll
        for (int p = 0; p < 2; p++) {
            s16x8 af[2], bfr[4];
            #pragma unroll
            for (int mi = 0; mi < 2; mi++)
                af[mi] = *(const s16x8*)&Ash[p][(wm * 32 + mi * 16 + lm) * 32 + sg];
            #pragma unroll
            for (int nj = 0; nj < 4; nj++)
                bfr[nj] = *(const s16x8*)&Bsh[p][(wn * 64 + nj * 16 + lm) * 32 + sg];
            #pragma unroll
            for (int mi = 0; mi < 2; mi++)
                #pragma unroll
                for (int nj = 0; nj < 4; nj++)
                    acc[mi][nj] = MFMA16(af[mi], bfr[nj], acc[mi][nj]);
        }
    }

    #pragma unroll
    for (int nj = 0; nj < 4; nj++) {
        int n = n0 + wn * 64 + nj * 16 + lm;
        float bv = bias[n];
        #pragma unroll
        for (int mi = 0; mi < 2; mi++) {
            #pragma unroll
            for (int r = 0; r < 4; r++) {
                int m = m0 + wm * 32 + mi * 16 + lq * 4 + r;
                out[(size_t)m * C_ + n] = acc[mi][nj][r] + bv;
            }
        }
    }
}

// ---------------------------------------------------------------------------
// softmax max+exp (exp2 domain, defer-max THR=8). S in/out; on exit S holds
// P = exp2(S - m). l accumulation is done by the caller via MFMA row-sum.
// lacc rows (q = quad*4+r) are rescaled together with O on a max update.
// ---------------------------------------------------------------------------
__device__ __forceinline__ void sm_maxexp(
    f32x4 S[4], float& mrow, f32x4& lacc, f32x4 O[4], int quad)
{
    float mt[4];
    #pragma unroll
    for (int t = 0; t < 4; t++)
        mt[t] = fmaxf(fmaxf(S[t][0], S[t][1]), fmaxf(S[t][2], S[t][3]));
    float rm = fmaxf(fmaxf(mt[0], mt[1]), fmaxf(mt[2], mt[3]));
    rm = fmaxf(rm, __shfl_xor(rm, 16, 64));
    rm = fmaxf(rm, __shfl_xor(rm, 32, 64));
    // defer-max: only rescale when some row grew by > 8 (=2^8 headroom)
    if (!__all(rm - mrow <= 8.f)) {
        float mnew  = fmaxf(mrow, rm);
        float alpha = fexp2(mrow - mnew);
        mrow = mnew;
        float al[4];
        #pragma unroll
        for (int r = 0; r < 4; r++) al[r] = __shfl(alpha, quad * 4 + r, 64);
        #pragma unroll
        for (int t = 0; t < 4; t++)
            #pragma unroll
            for (int r = 0; r < 4; r++) O[t][r] *= al[r];
        #pragma unroll
        for (int r = 0; r < 4; r++) lacc[r] *= al[r];
    }
    #pragma unroll
    for (int t = 0; t < 4; t++)
        #pragma unroll
        for (int r = 0; r < 4; r++) S[t][r] = fexp2(S[t][r] - mrow);
}

// ---------------------------------------------------------------------------
// MFMA flash attention, S^T layout, PAIRED q-tiles per block. Grid 512.
// K/V LDS double-buffered, ONE __syncthreads per iteration (R28). NEW:
// l[q] = mfma(P, ones) row-sum on the matrix pipe (replaces VALU sum tree
// + shfl; epilogue li[r] = 1/l[r] directly). Max tree via v_max3 nesting.
// LDS 64KB (2 blocks/CU), XOR-swizzled, setprio, exp2 defer-max softmax.
// ---------------------------------------------------------------------------
__global__ __launch_bounds__(256, 2) void attn_mfma(
    const short* __restrict__ Qh, const short* __restrict__ Ql,
    const short* __restrict__ Kh, const short* __restrict__ Kl,
    const short* __restrict__ VT, short* __restrict__ Yb)
{
    __shared__ short Ksh[2][64][64], Ksl[2][64][64];   // [buf][key][d]
    __shared__ short Vt [2][64][64];                   // [buf][d][key]
    __shared__ short Ps [4][2][16][64];                // per-wave P slabs

    const int tid  = threadIdx.x;
    const int wave = tid >> 6, lane = tid & 63;
    const int lm   = lane & 15, quad = lane >> 4;
    const int swz  = (lm & 7) << 3;              // read-side XOR (shorts)

    const int bid = blockIdx.x;                  // 512 blocks
    const int xcd = bid & 7;
    const int r_  = bid >> 3;                    // 0..63 per XCD
    const int bhl = r_ & 3;
    const int u   = r_ >> 2;                     // 0..15
    const int g_  = u >> 3, j_ = u & 7;
    const int j   = g_ ? (15 - j_) : j_;         // CU slot pairs j with 15-j
    const int bh  = xcd * 4 + bhl;
    const int b   = bh >> 4, h = bh & (H_ - 1);
    const int qtA = j, qtB = 31 - j;
    const int q0A = qtA * 64, q0B = qtB * 64;
    const size_t base  = (size_t)bh * T_ * D_;   // Q,K: [b,h,t,d]
    const size_t vbase = (size_t)bh * D_ * T_;   // VT:  [b,h,d,t]

    const int src = tid >> 3;                    // staging row 0..31 (+32)
    const int sch = (tid & 7) * 8;               // linear global col (shorts)
    const int wsw = sch ^ ((src & 7) << 3);      // swizzled LDS write col

    // all-ones bf16 B-frag for the l row-sum MFMA
    s16x8 ones;
    #pragma unroll
    for (int z = 0; z < 8; z++) ones[z] = (short)0x3F80;

    // ---- Q frags direct from global (L2-hit, once per block) ----
    s16x8 bqhA[2], bqlA[2], bqhB[2], bqlB[2];
    #pragma unroll
    for (int kc = 0; kc < 2; kc++) {
        size_t ga = base + (size_t)(q0A + wave * 16 + lm) * D_ + kc * 32 + quad * 8;
        size_t gb = base + (size_t)(q0B + wave * 16 + lm) * D_ + kc * 32 + quad * 8;
        bqhA[kc] = *(const s16x8*)&Qh[ga];
        bqlA[kc] = *(const s16x8*)&Ql[ga];
        bqhB[kc] = *(const s16x8*)&Qh[gb];
        bqlB[kc] = *(const s16x8*)&Ql[gb];
    }

    // ---- prologue: tile 0 -> regs -> buf0; issue tile 1 loads ----
    s16x8 pkh[2], pkl[2], pvt[2];
    #pragma unroll
    for (int i = 0; i < 2; i++) {
        int row = i * 32 + src;
        size_t gk = base + (size_t)row * D_ + sch;
        pkh[i] = *(const s16x8*)&Kh[gk];
        pkl[i] = *(const s16x8*)&Kl[gk];
        pvt[i] = *(const s16x8*)&VT[vbase + (size_t)row * T_ + sch];
    }
    #pragma unroll
    for (int i = 0; i < 2; i++) {
        int row = i * 32 + src;
        *(s16x8*)&Ksh[0][row][wsw] = pkh[i];
        *(s16x8*)&Ksl[0][row][wsw] = pkl[i];
        *(s16x8*)&Vt [0][row][wsw] = pvt[i];
    }
    {   // qtB >= 16, so tile 1 always exists
        #pragma unroll
        for (int i = 0; i < 2; i++) {
            int row = i * 32 + src;
            size_t gk = base + (size_t)(64 + row) * D_ + sch;
            pkh[i] = *(const s16x8*)&Kh[gk];
            pkl[i] = *(const s16x8*)&Kl[gk];
            pvt[i] = *(const s16x8*)&VT[vbase + (size_t)row * T_ + 64 + sch];
        }
    }
    __syncthreads();

    float mA = -INFINITY, mB = -INFINITY;
    f32x4 lA = {}, lB = {};
    f32x4 OA[4] = {}, OB[4] = {};

    for (int kt = 0; kt <= qtB; kt++) {
        const int cur = kt & 1;

        // ---- write tile kt+1 -> buf[cur^1]; issue loads for kt+2 ----
        // (overlaps compute below; drained by end-of-iter __syncthreads)
        if (kt < qtB) {
            #pragma unroll
            for (int i = 0; i < 2; i++) {
                int row = i * 32 + src;
                *(s16x8*)&Ksh[cur ^ 1][row][wsw] = pkh[i];
                *(s16x8*)&Ksl[cur ^ 1][row][wsw] = pkl[i];
                *(s16x8*)&Vt [cur ^ 1][row][wsw] = pvt[i];
            }
            if (kt + 2 <= qtB) {
                #pragma unroll
                for (int i = 0; i < 2; i++) {
                    int row = i * 32 + src;
                    size_t gk = base + (size_t)((kt + 2) * 64 + row) * D_ + sch;
                    pkh[i] = *(const s16x8*)&Kh[gk];
                    pkl[i] = *(const s16x8*)&Kl[gk];
                    pvt[i] = *(const s16x8*)&VT[vbase + (size_t)row * T_ + (kt + 2) * 64 + sch];
                }
            }
        }

        const bool doA = (kt <= qtA);
        const int  qg  = wave * 16 + lm;

        f32x4 SB[4] = {}, SA[4] = {};
        __builtin_amdgcn_s_setprio(1);
        if (doA) {
            // dual: one k-frag read feeds 6 MFMAs (two independent chains)
            #pragma unroll
            for (int t = 0; t < 4; t++)
                #pragma unroll
                for (int kc = 0; kc < 2; kc++) {
                    s16x8 kh8 = *(const s16x8*)&Ksh[cur][t * 16 + lm][(kc * 32 + quad * 8) ^ swz];
                    s16x8 kl8 = *(const s16x8*)&Ksl[cur][t * 16 + lm][(kc * 32 + quad * 8) ^ swz];
                    SB[t] = MFMA16(kh8, bqhB[kc], SB[t]);
                    SB[t] = MFMA16(kl8, bqhB[kc], SB[t]);
                    SB[t] = MFMA16(kh8, bqlB[kc], SB[t]);
                    SA[t] = MFMA16(kh8, bqhA[kc], SA[t]);
                    SA[t] = MFMA16(kl8, bqhA[kc], SA[t]);
                    SA[t] = MFMA16(kh8, bqlA[kc], SA[t]);
                }
        } else {
            #pragma unroll
            for (int t = 0; t < 4; t++)
                #pragma unroll
                for (int kc = 0; kc < 2; kc++) {
                    s16x8 kh8 = *(const s16x8*)&Ksh[cur][t * 16 + lm][(kc * 32 + quad * 8) ^ swz];
                    s16x8 kl8 = *(const s16x8*)&Ksl[cur][t * 16 + lm][(kc * 32 + quad * 8) ^ swz];
                    SB[t] = MFMA16(kh8, bqhB[kc], SB[t]);
                    SB[t] = MFMA16(kl8, bqhB[kc], SB[t]);
                    SB[t] = MFMA16(kh8, bqlB[kc], SB[t]);
                }
        }
        __builtin_amdgcn_s_setprio(0);

        // causal masks (scale pre-folded into Q)
        if (kt == qtB) {
            #pragma unroll
            for (int t = 0; t < 4; t++)
                #pragma unroll
                for (int r = 0; r < 4; r++)
                    if ((t * 16 + quad * 4 + r) > qg) SB[t][r] = -INFINITY;
        }
        if (kt == qtA) {
            #pragma unroll
            for (int t = 0; t < 4; t++)
                #pragma unroll
                for (int r = 0; r < 4; r++)
                    if ((t * 16 + quad * 4 + r) > qg) SA[t][r] = -INFINITY;
        }

        // ---- softmax max+exp (dual chains independent); l via MFMA below ----
        sm_maxexp(SB, mB, lB, OB, quad);
        if (doA) sm_maxexp(SA, mA, lA, OA, quad);

        // ---- P^T -> Ps (truncating bf16; P in [0, 256]) ----
        #pragma unroll
        for (int t = 0; t < 4; t++) {
            s16x4 p;
            #pragma unroll
            for (int r = 0; r < 4; r++)
                p[r] = (short)(__float_as_uint(SB[t][r]) >> 16);
            *(s16x4*)&Ps[wave][0][lm][(t * 16 + quad * 4) ^ swz] = p;
        }
        if (doA) {
            #pragma unroll
            for (int t = 0; t < 4; t++) {
                s16x4 p;
                #pragma unroll
                for (int r = 0; r < 4; r++)
                    p[r] = (short)(__float_as_uint(SA[t][r]) >> 16);
                *(s16x4*)&Ps[wave][1][lm][(t * 16 + quad * 4) ^ swz] = p;
            }
        }
        // wave-private slabs: no barrier (lgkmcnt ordering within wave)

        // ---- O += P V and l += P·1: shared Vt frag feeds both tiles ----
        s16x8 apB[2], apA[2];
        #pragma unroll
        for (int kc = 0; kc < 2; kc++)
            apB[kc] = *(const s16x8*)&Ps[wave][0][lm][(kc * 32 + quad * 8) ^ swz];
        __builtin_amdgcn_s_setprio(1);
        if (doA) {
            #pragma unroll
            for (int kc = 0; kc < 2; kc++)
                apA[kc] = *(const s16x8*)&Ps[wave][1][lm][(kc * 32 + quad * 8) ^ swz];
            #pragma unroll
            for (int kc = 0; kc < 2; kc++) {
                lB = MFMA16(apB[kc], ones, lB);
                lA = MFMA16(apA[kc], ones, lA);
            }
            #pragma unroll
            for (int t = 0; t < 4; t++)
                #pragma unroll
                for (int kc = 0; kc < 2; kc++) {
                    s16x8 bv = *(const s16x8*)&Vt[cur][t * 16 + lm][(kc * 32 + quad * 8) ^ swz];
                    OB[t] = MFMA16(apB[kc], bv, OB[t]);
                    OA[t] = MFMA16(apA[kc], bv, OA[t]);
                }
        } else {
            #pragma unroll
            for (int kc = 0; kc < 2; kc++)
                lB = MFMA16(apB[kc], ones, lB);
            #pragma unroll
            for (int t = 0; t < 4; t++)
                #pragma unroll
                for (int kc = 0; kc < 2; kc++) {
                    s16x8 bv = *(const s16x8*)&Vt[cur][t * 16 + lm][(kc * 32 + quad * 8) ^ swz];
                    OB[t] = MFMA16(apB[kc], bv, OB[t]);
                }
        }
        __builtin_amdgcn_s_setprio(0);

        __syncthreads();   // reads of buf[cur] done; writes of buf[cur^1] visible
    }

    // ---- epilogue: O row q = wave*16+quad*4+r, col d = t*16+lm ----
    // l rows already match O rows (MFMA C layout) -> no shuffle needed.
    float liA[4], liB[4];
    #pragma unroll
    for (int r = 0; r < 4; r++) {
        liA[r] = 1.0f / lA[r];
        liB[r] = 1.0f / lB[r];
    }
    #pragma unroll
    for (int t = 0; t < 4; t++)
        #pragma unroll
        for (int r = 0; r < 4; r++) {
            int d  = t * 16 + lm;
            int qa = q0A + wave * 16 + quad * 4 + r;
            int qb = q0B + wave * 16 + quad * 4 + r;
            Yb[((size_t)b * T_ + qa) * C_ + h * D_ + d] =
                (short)f2b(OA[t][r] * liA[r]);
            Yb[((size_t)b * T_ + qb) * C_ + h * D_ + d] =
                (short)f2b(OB[t][r] * liB[r]);
        }
}

// ---------------------------------------------------------------------------
extern "C" void kernel_launch(void* const* d_in, const int* in_sizes, int n_in,
                              void* d_out, int out_size, void* d_ws, size_t ws_size,
                              hipStream_t stream)
{
    const float* x      = (const float*)d_in[0];
    const float* W_attn = (const float*)d_in[1];
    const float* b_attn = (const float*)d_in[2];
    const float* W_proj = (const float*)d_in[3];
    const float* b_proj = (const float*)d_in[4];
    float* out = (float*)d_out;

    char* ws = (char*)d_ws;
    const size_t MB = 1024 * 1024;
    short* Qh   = (short*)(ws);            // 8 MB  [ 0, 8)
    short* Ql   = (short*)(ws +  8 * MB);  // 8 MB  [ 8,16)
    short* Kh   = (short*)(ws + 16 * MB);  // 8 MB  [16,24)
    short* Kl   = (short*)(ws + 24 * MB);  // 8 MB  [24,32)
    short* xh   = (short*)(ws + 32 * MB);  // 8 MB  [32,40)  dead after qkv_v
    short* xl   = (short*)(ws + 40 * MB);  // 8 MB  [40,48)  dead after qkv_qk
    short* WaTh = (short*)(ws + 48 * MB);  // 6 MB  [48,54)
    short* WaTl = (short*)(ws + 54 * MB);  // 6 MB  [54,60)
    short* WpT  = (short*)(ws + 60 * MB);  // 2 MB  [60,62)
    short* VT   = (short*)(ws + 40 * MB);  // 8 MB  aliases xl (born at qkv_v)
    short* Yb   = (short*)(ws + 32 * MB);  // 8 MB  aliases xh (born at attn)

    cvt_all<<<dim3(3072), 256, 0, stream>>>(x, xh, xl, W_attn, WaTh, WaTl,
                                            W_proj, WpT);

    qkv_qk <<<dim3(16, 32), 256, 0, stream>>>(xh, xl, WaTh, WaTl, b_attn,
                                              Qh, Ql, Kh, Kl);
    qkv_v  <<<dim3(8, 64), 256, 0, stream>>>(xh, WaTh + (size_t)2048 * C_,
                                             b_attn + 2048, VT);
    attn_mfma<<<dim3(512), 256, 0, stream>>>(Qh, Ql, Kh, Kl, VT, Yb);
    proj_mfma<<<dim3(8, 64), 256, 0, stream>>>(Yb, WpT, b_proj, out);
}